// Round 1
// baseline (520.457 us; speedup 1.0000x reference)
//
#include <hip/hip_runtime.h>
#include <math.h>

// Problem constants
#define Bsz  4096
#define Tlen 512
#define NE   30
#define NIN  5
#define HD10 10
#define B10  (Bsz*HD10)   // per-head plane: 40960 floats

typedef _Float16 h2v  __attribute__((ext_vector_type(2)));
typedef _Float16 f16x8 __attribute__((ext_vector_type(8)));
typedef float    f32x4 __attribute__((ext_vector_type(4)));

__device__ __forceinline__ float fexp2(float x){ return __builtin_amdgcn_exp2f(x); }
__device__ __forceinline__ float frcp (float x){ return __builtin_amdgcn_rcpf(x); }
#define L2E 1.4426950408889634f

__device__ __forceinline__ void loadarr32(float arr[32], const float* bufrow){
  const float4* p4 = (const float4*)bufrow;
  #pragma unroll
  for (int q4=0;q4<8;q4++){ float4 vv=p4[q4]; arr[4*q4]=vv.x; arr[4*q4+1]=vv.y; arr[4*q4+2]=vv.z; arr[4*q4+3]=vv.w; }
}

// ---------------------------------------------------------------------------
// Kernel 1 (R11: barrier-free single-wave chain).
// One WAVE (64 thr) per 16-batch chain; grid 256.
// The cross-wave h exchange (pack->ds_write->barrier->ds_read, ~950 of the
// 1251 cyc/step in R8) is eliminated by a row-permuted A layout:
//   dim(T, m) = 8*(m>>2) + 4*T + (m&3)
// so D[m=4q+r] of tiles T=0,1 lands h dims {8q..8q+7} in lane (q,n) --
// exactly the B-frag k=8q+j this lane must supply next step. The recurrence
// is now MFMA -> lane-local activations -> pack f16x8 -> MFMA, fully
// in-register. x-projection MFMAs software-pipelined one step ahead
// (x ds_reads two steps ahead) to stay off the critical path.
// Garbage dims 30,31 (q=3,T=1,r>=2): A rows zero + bias zero => preact==0
// => gv=0, c stays exactly 0, h stays exactly 0 -> safe in the k=30,31
// B slots (multiplied by zeroed A columns anyway).
// Fragment layouts (m89/m120-verified):
//   A[m=lane&15][k=(lane>>4)*8+j], B[k=(lane>>4)*8+j][n=lane&15],
//   D[m=(lane>>4)*4+r][n=lane&15].
// ---------------------------------------------------------------------------
extern "C" __global__ void __launch_bounds__(64,1)
lstm_k(const float* __restrict__ input, const float* __restrict__ w_ih,
       const float* __restrict__ w_hh, const float* __restrict__ b_ih,
       const float* __restrict__ b_hh, const float* __restrict__ in_proj_w,
       const float* __restrict__ in_proj_b,
       float* __restrict__ qo, float* __restrict__ ko, float* __restrict__ vo,
       float* __restrict__ ho)
{
  __shared__ __align__(16) float xstf[16*390];   // x: [n][t][6pad], 24.4 KB
  const int lane = threadIdx.x & 63;
  const int n    = lane & 15;
  const int quad = lane >> 4;
  const int b0   = blockIdx.x * 16;

  // ---- build A-frags (row-permuted dim mapping) + bias C-init ----
  f16x8 ah[2][4], ax[2][4];
  f32x4 bi[2][4];
  #pragma unroll
  for (int T=0; T<2; ++T){
    #pragma unroll
    for (int G=0; G<4; ++G){
      const float sG = (G==2) ? (-2.f*L2E) : (-L2E);   // g gate: tanh via 2sig(2x)-1
      const int dA = 8*(n>>2) + 4*T + (n&3);           // dim for A row m=n
      const bool rv = (dA < NE);
      const int grow = rv ? (NE*G + dA) : 0;
      #pragma unroll
      for (int j=0;j<8;++j){
        const int k = quad*8 + j;
        ah[T][G][j] = (rv && k < NE) ? (_Float16)(sG*w_hh[grow*NE + k]) : (_Float16)0;
        ax[T][G][j] = (rv && quad==0 && j < NIN) ? (_Float16)(sG*w_ih[grow*NIN + j]) : (_Float16)0;
      }
      #pragma unroll
      for (int r=0;r<4;++r){
        const int d = 8*quad + 4*T + r;                // dim for D row m=4q+r
        bi[T][G][r] = (d < NE) ? sG*(b_ih[NE*G+d] + b_hh[NE*G+d]) : 0.f;
      }
    }
  }

  float c[8], h[8];
  #pragma unroll
  for (int s=0;s<8;++s){ c[s]=0.f; h[s]=0.f; }
  f16x8 bh = (f16x8)(_Float16)0;                       // h state IS the B-frag

  const float2* x2p = (const float2*)xstf;
  const int xb2 = n*195;                               // float2 base for this batch

  f32x4 Cx[2][4];                                      // x-proj for step tl (pipelined)
  float2 xA0, xA1, xA2;                                // raw x for step tl+1

  for (int tc = 0; tc < Tlen; tc += 64) {
    __syncthreads();   // xstf reuse safety (prev chunk reads done)
    // stage 64 steps x 16 batches x 5 inputs -> padded [n][t][6] (float4 global loads)
    for (int i4 = lane; i4 < 1280; i4 += 64){
      const int nn = i4/80, e4 = i4%80;
      const float4 v4 = *(const float4*)(input + (size_t)(b0+nn)*(Tlen*NIN) + tc*NIN + e4*4);
      #pragma unroll
      for (int u=0;u<4;++u){
        const int e = e4*4+u;
        xstf[nn*390 + (e/5)*6 + (e%5)] = (&v4.x)[u];
      }
    }
    __syncthreads();
    // prime pipeline: Cx <- x-proj(t=0); xA <- x(t=1)
    {
      const float2 a0=x2p[xb2], a1=x2p[xb2+1], a2=x2p[xb2+2];
      union { f16x8 v; h2v h2[4]; } U;
      U.h2[0].x=(_Float16)a0.x; U.h2[0].y=(_Float16)a0.y;
      U.h2[1].x=(_Float16)a1.x; U.h2[1].y=(_Float16)a1.y;
      U.h2[2].x=(_Float16)a2.x; U.h2[2].y=(_Float16)0;
      U.h2[3]=(h2v)(_Float16)0;
      #pragma unroll
      for (int T=0;T<2;++T)
        #pragma unroll
        for (int G=0;G<4;++G)
          Cx[T][G] = __builtin_amdgcn_mfma_f32_16x16x32_f16(ax[T][G], U.v, bi[T][G], 0,0,0);
      xA0 = x2p[xb2+3]; xA1 = x2p[xb2+4]; xA2 = x2p[xb2+5];
    }
    #pragma unroll 1
    for (int tl = 0; tl < 64; ++tl) {
      // 1) recurrent MFMAs (the critical path): bh ready from previous step
      f32x4 C[2][4];
      #pragma unroll
      for (int T=0;T<2;++T)
        #pragma unroll
        for (int G=0;G<4;++G)
          C[T][G] = __builtin_amdgcn_mfma_f32_16x16x32_f16(ah[T][G], bh, Cx[T][G], 0,0,0);
      // 2) next step's x-projection from registers (no LDS wait on path)
      {
        union { f16x8 v; h2v h2[4]; } U;
        U.h2[0].x=(_Float16)xA0.x; U.h2[0].y=(_Float16)xA0.y;
        U.h2[1].x=(_Float16)xA1.x; U.h2[1].y=(_Float16)xA1.y;
        U.h2[2].x=(_Float16)xA2.x; U.h2[2].y=(_Float16)0;
        U.h2[3]=(h2v)(_Float16)0;
        #pragma unroll
        for (int T=0;T<2;++T)
          #pragma unroll
          for (int G=0;G<4;++G)
            Cx[T][G] = __builtin_amdgcn_mfma_f32_16x16x32_f16(ax[T][G], U.v, bi[T][G], 0,0,0);
      }
      // 3) issue ds_reads for x(tl+2) (wrap reads are discarded by next prime)
      {
        const int t2 = (tl+2) & 63;
        const int base0 = xb2 + t2*3;
        xA0 = x2p[base0]; xA1 = x2p[base0+1]; xA2 = x2p[base0+2];
      }
      // 4) activations: preacts pre-scaled; sig = rcp(1+exp2(C));
      //    g gate: tanh = 2*rcp(1+exp2(C)) - 1 (C already -2L2E*a)
      #pragma unroll
      for (int T=0;T<2;++T){
        #pragma unroll
        for (int r=0;r<4;++r){
          const int s = 4*T + r;
          const float iv = frcp(1.f + fexp2(C[T][0][r]));
          const float fv = frcp(1.f + fexp2(C[T][1][r]));
          const float gv = fmaf(2.f, frcp(1.f + fexp2(C[T][2][r])), -1.f);
          const float ov = frcp(1.f + fexp2(C[T][3][r]));
          c[s] = fmaf(fv, c[s], iv*gv);
          const float r2 = frcp(1.f + fexp2((2.f*L2E)*c[s]));
          h[s] = ov * fmaf(-2.f, r2, 1.f);
        }
      }
      // 5) pack h -> bh (in-lane: slot j == k-8q == dim-8q)
      {
        union { f16x8 v; h2v h2[4]; } P;
        #pragma unroll
        for (int p=0;p<4;++p){ P.h2[p].x=(_Float16)h[2*p]; P.h2[p].y=(_Float16)h[2*p+1]; }
        bh = P.v;
      }
    }
  }

  // ---- tail: stash fp32 h,c; project q(h), k(c), v(c) ----
  float* hf = xstf;            // [16][36]
  float* cf = xstf + 16*36;
  __syncthreads();
  {
    float4 hv0; hv0.x=h[0]; hv0.y=h[1]; hv0.z=h[2]; hv0.w=h[3];
    float4 hv1; hv1.x=h[4]; hv1.y=h[5]; hv1.z=h[6]; hv1.w=h[7];
    float4 cv0; cv0.x=c[0]; cv0.y=c[1]; cv0.z=c[2]; cv0.w=c[3];
    float4 cv1; cv1.x=c[4]; cv1.y=c[5]; cv1.z=c[6]; cv1.w=c[7];
    *(float4*)(&hf[n*36 + 8*quad    ]) = hv0;   // dims 8q..8q+3
    *(float4*)(&hf[n*36 + 8*quad + 4]) = hv1;   // dims 8q+4..8q+7 (30,31 = exact 0)
    *(float4*)(&cf[n*36 + 8*quad    ]) = cv0;
    *(float4*)(&cf[n*36 + 8*quad + 4]) = cv1;
  }
  __syncthreads();
  for (int i = lane; i < 16*NE; i += 64){
    const int nn = i/NE, d = i%NE;
    ho[(size_t)(b0+nn)*NE + d] = hf[nn*36 + d];
  }
  const float QS = 0.31622776601683794f;     // 1/sqrt(10)
  for (int i = lane; i < 90*16; i += 64){
    const int o  = i % 90;
    const int nn = i / 90;
    const float* wrow = in_proj_w + o*NE;
    const float* src  = (o < NE) ? &hf[nn*36] : &cf[nn*36];
    float acc = in_proj_b[o];
    #pragma unroll
    for (int k2=0;k2<NE;k2++) acc = fmaf(wrow[k2], src[k2], acc);
    const int b = b0 + nn;
    if (o < 30)      { qo[(o/10)*B10 + b*10 + (o%10)] = acc * QS; }
    else if (o < 60) { const int u=o-30; ko[(u/10)*B10 + b*10 + (u%10)] = acc; }
    else             { const int u=o-60; vo[(u/10)*B10 + b*10 + (u%10)] = acc; }
  }
}

// ---------------------------------------------------------------------------
// Kernel 2 (R10: cooperative LDS staging): flash attention partials.
// Thread = query. grid (16 qblocks, 3 heads, NS), block 256.
// ---------------------------------------------------------------------------
extern "C" __global__ void __launch_bounds__(256)
attn_part(const float* __restrict__ q, const float* __restrict__ k,
          const float* __restrict__ v, float* __restrict__ part, int nkeys)
{
  __shared__ __align__(16) float kst[640];   // 64 keys x 10
  __shared__ __align__(16) float vst[640];
  const int t    = threadIdx.x;
  const int qr   = blockIdx.x*256 + t;
  const int head = blockIdx.y;
  const int ks   = blockIdx.z;
  const float* kh = k + (size_t)head*B10;
  const float* vh = v + (size_t)head*B10;
  float qreg[10];
  {
    const float2* qp = (const float2*)(q + (size_t)head*B10 + (size_t)qr*10);
    #pragma unroll
    for (int i=0;i<5;i++){ float2 t2=qp[i]; qreg[2*i]=t2.x; qreg[2*i+1]=t2.y; }
  }
  float m = -INFINITY, l = 0.f, acc[10];
  #pragma unroll
  for (int d=0;d<10;d++) acc[d]=0.f;

  const int k0 = ks * nkeys;
  const int nt = nkeys >> 6;           // 64-key tiles
  #pragma unroll 1
  for (int ti=0; ti<nt; ++ti){
    const int kt0 = k0 + (ti<<6);
    __syncthreads();                   // previous tile's reads complete
    {
      const float4* ksrc = (const float4*)(kh + (size_t)kt0*10);
      const float4* vsrc = (const float4*)(vh + (size_t)kt0*10);
      for (int i=t; i<320; i+=256){
        if (i < 160) ((float4*)kst)[i]     = ksrc[i];
        else         ((float4*)vst)[i-160] = vsrc[i-160];
      }
    }
    __syncthreads();                   // staging visible
    #pragma unroll 1
    for (int c8=0; c8<64; c8+=8){
      float s[8];
      #pragma unroll
      for (int u=0;u<8;u++){
        const float2* kp = (const float2*)(kst + (c8+u)*10);
        float sv = 0.f;
        #pragma unroll
        for (int i=0;i<5;i++){ float2 kk=kp[i]; sv=fmaf(qreg[2*i],kk.x,sv); sv=fmaf(qreg[2*i+1],kk.y,sv); }
        s[u]=sv;
      }
      float mc = s[0];
      #pragma unroll
      for (int u=1;u<8;u++) mc = fmaxf(mc, s[u]);
      const float mnew = fmaxf(m, mc);
      const float corr = fexp2(L2E*(m - mnew));   // m=-inf first chunk -> 0
      l *= corr;
      #pragma unroll
      for (int d=0;d<10;d++) acc[d]*=corr;
      #pragma unroll
      for (int u=0;u<8;u++){
        const float p = fexp2(L2E*(s[u]-mnew));
        l += p;
        const float2* vp = (const float2*)(vst + (c8+u)*10);
        #pragma unroll
        for (int i=0;i<5;i++){ float2 vv=vp[i]; acc[2*i]=fmaf(p,vv.x,acc[2*i]); acc[2*i+1]=fmaf(p,vv.y,acc[2*i+1]); }
      }
      m = mnew;
    }
  }
  float* pp = part + ((size_t)(head*Bsz + qr)*gridDim.z + ks)*12;
  pp[0]=m; pp[1]=l;
  #pragma unroll
  for (int d=0;d<10;d++) pp[2+d]=acc[d];
}

// ---------------------------------------------------------------------------
// Kernel 3 (R10: LDS weights): fused merge + out_proj + LN + MLP + LN + head.
// One wave per row. Weight matrices staged to LDS once per block.
// ---------------------------------------------------------------------------
extern "C" __global__ void __launch_bounds__(256)
tail_k(const float* __restrict__ part, int ns, const float* __restrict__ hn,
       const float* __restrict__ out_proj_w, const float* __restrict__ out_proj_b,
       const float* __restrict__ fc1_w, const float* __restrict__ fc1_b,
       const float* __restrict__ fc2_w, const float* __restrict__ fc2_b,
       const float* __restrict__ ln_g, const float* __restrict__ ln_b,
       const float* __restrict__ out_w, const float* __restrict__ out_b,
       float* __restrict__ out)
{
  __shared__ __align__(16) float buf[4][32];
  __shared__ float wl[2880];   // [0]=out_proj_w 900, [900]=fc1_w, [1800]=fc2_w, [2700]=out_w 90
  const int tidb = threadIdx.x;
  for (int i=tidb;i<900;i+=256) wl[i]       = out_proj_w[i];
  for (int i=tidb;i<900;i+=256) wl[900+i]   = fc1_w[i];
  for (int i=tidb;i<900;i+=256) wl[1800+i]  = fc2_w[i];
  if (tidb < 90) wl[2700+tidb] = out_w[tidb];
  const int wave = tidb >> 6;
  const int lane = tidb & 63;
  const int b = blockIdx.x*4 + wave;
  const bool act = (lane < NE);
  if (lane < 32) buf[wave][lane] = 0.f;
  __syncthreads();
  if (act) {
    const int head = lane/10, dd = lane%10;
    const float* p = part + ((size_t)(head*Bsz + b)*ns)*12;
    float M = -INFINITY, L = 0.f, O = 0.f;
    for (int i=0;i<ns;i++){
      const float mi = p[i*12], li = p[i*12+1], ai = p[i*12+2+dd];
      const float Mn = fmaxf(M, mi);
      const float cw = fexp2(L2E*(M - Mn));
      const float wi = fexp2(L2E*(mi - Mn));
      L = fmaf(li, wi, L*cw);
      O = fmaf(ai, wi, O*cw);
      M = Mn;
    }
    buf[wave][lane] = O / L;
  }
  __builtin_amdgcn_wave_barrier();
  float arr[32];
  loadarr32(arr, &buf[wave][0]);
  const float hv = act ? hn[b*NE+lane] : 0.f;
  float x = 0.f;
  if (act) {
    float a = out_proj_b[lane];
    #pragma unroll
    for (int k2=0;k2<NE;k2++) a = fmaf(wl[lane*NE+k2], arr[k2], a);
    x = a + hv;                       // attn_out + h_n
  }
  // LN1
  __builtin_amdgcn_wave_barrier();
  if (act) buf[wave][lane] = x;
  __builtin_amdgcn_wave_barrier();
  loadarr32(arr, &buf[wave][0]);
  float s1=0.f, s2=0.f;
  #pragma unroll
  for (int k2=0;k2<32;k2++){ s1+=arr[k2]; s2=fmaf(arr[k2],arr[k2],s2); }
  float mu = s1*(1.f/30.f);
  float var = s2*(1.f/30.f) - mu*mu;
  float rs = rsqrtf(var + 1e-5f);
  float x1 = 0.f;
  if (act) x1 = fmaf((x-mu)*rs, ln_g[lane], ln_b[lane]);
  // fc1 + exact GELU
  __builtin_amdgcn_wave_barrier();
  if (act) buf[wave][lane] = x1;
  __builtin_amdgcn_wave_barrier();
  loadarr32(arr, &buf[wave][0]);
  float gv = 0.f;
  if (act) {
    float a = fc1_b[lane];
    #pragma unroll
    for (int k2=0;k2<NE;k2++) a = fmaf(wl[900+lane*NE+k2], arr[k2], a);
    gv = 0.5f*a*(1.f + erff(a*0.70710678118654752f));
  }
  // fc2
  __builtin_amdgcn_wave_barrier();
  if (act) buf[wave][lane] = gv;
  __builtin_amdgcn_wave_barrier();
  loadarr32(arr, &buf[wave][0]);
  float y = 0.f;
  if (act) {
    float a = fc2_b[lane];
    #pragma unroll
    for (int k2=0;k2<NE;k2++) a = fmaf(wl[1800+lane*NE+k2], arr[k2], a);
    y = x1 + a;                        // residual x1 + fc
  }
  // LN2
  __builtin_amdgcn_wave_barrier();
  if (act) buf[wave][lane] = y;
  __builtin_amdgcn_wave_barrier();
  loadarr32(arr, &buf[wave][0]);
  s1=0.f; s2=0.f;
  #pragma unroll
  for (int k2=0;k2<32;k2++){ s1+=arr[k2]; s2=fmaf(arr[k2],arr[k2],s2); }
  mu = s1*(1.f/30.f);
  var = s2*(1.f/30.f) - mu*mu;
  rs = rsqrtf(var + 1e-5f);
  float x2 = 0.f;
  if (act) x2 = fmaf((y-mu)*rs, ln_g[lane], ln_b[lane]);
  // head: [3,30]
  __builtin_amdgcn_wave_barrier();
  if (act) buf[wave][lane] = x2;
  __builtin_amdgcn_wave_barrier();
  loadarr32(arr, &buf[wave][0]);
  if (lane < 3) {
    float a = out_b[lane];
    #pragma unroll
    for (int k2=0;k2<NE;k2++) a = fmaf(wl[2700+lane*NE+k2], arr[k2], a);
    out[b*3 + lane] = a;
  }
}

extern "C" void kernel_launch(void* const* d_in, const int* in_sizes, int n_in,
                              void* d_out, int out_size, void* d_ws, size_t ws_size,
                              hipStream_t stream)
{
  const float* input      = (const float*)d_in[0];
  const float* w_ih       = (const float*)d_in[1];
  const float* w_hh       = (const float*)d_in[2];
  const float* b_ih       = (const float*)d_in[3];
  const float* b_hh       = (const float*)d_in[4];
  const float* in_proj_w  = (const float*)d_in[5];
  const float* in_proj_b  = (const float*)d_in[6];
  const float* out_proj_w = (const float*)d_in[7];
  const float* out_proj_b = (const float*)d_in[8];
  const float* fc1_w      = (const float*)d_in[9];
  const float* fc1_b      = (const float*)d_in[10];
  const float* fc2_w      = (const float*)d_in[11];
  const float* fc2_b      = (const float*)d_in[12];
  const float* ln_g       = (const float*)d_in[13];
  const float* ln_b       = (const float*)d_in[14];
  const float* out_w      = (const float*)d_in[15];
  const float* out_b      = (const float*)d_in[16];

  float* ws = (float*)d_ws;
  float* qo   = ws;                 // [3][4096][10]
  float* ko   = ws + 122880;        // [3][4096][10]
  float* vo   = ws + 245760;        // [3][4096][10]
  float* hn   = ws + 368640;        // [4096][30]
  float* part = ws + 491520;        // [3][4096][NS][12]

  const size_t need16 = ((size_t)491520 + (size_t)3*4096*16*12) * 4;
  const int NS = (ws_size >= need16) ? 16 : 8;

  lstm_k<<<Bsz/16, 64, 0, stream>>>(input, w_ih, w_hh, b_ih, b_hh,
                                    in_proj_w, in_proj_b, qo, ko, vo, hn);
  attn_part<<<dim3(Bsz/256, 3, NS), 256, 0, stream>>>(qo, ko, vo, part, Bsz/NS);
  tail_k<<<Bsz/4, 256, 0, stream>>>(part, NS, hn, out_proj_w, out_proj_b,
                                    fc1_w, fc1_b, fc2_w, fc2_b,
                                    ln_g, ln_b, out_w, out_b, (float*)d_out);
}

// Round 3
// 360.566 us; speedup vs baseline: 1.4434x; 1.4434x over previous
//
#include <hip/hip_runtime.h>
#include <math.h>

// Problem constants
#define Bsz  4096
#define Tlen 512
#define NE   30
#define NIN  5
#define HD10 10
#define B10  (Bsz*HD10)   // per-head plane: 40960 floats

typedef _Float16 h2v  __attribute__((ext_vector_type(2)));
typedef _Float16 f16x8 __attribute__((ext_vector_type(8)));
typedef float    f32x4 __attribute__((ext_vector_type(4)));

__device__ __forceinline__ float fexp2(float x){ return __builtin_amdgcn_exp2f(x); }
__device__ __forceinline__ float frcp (float x){ return __builtin_amdgcn_rcpf(x); }
#define L2E 1.4426950408889634f

__device__ __forceinline__ void loadarr32(float arr[32], const float* bufrow){
  const float4* p4 = (const float4*)bufrow;
  #pragma unroll
  for (int q4=0;q4<8;q4++){ float4 vv=p4[q4]; arr[4*q4]=vv.x; arr[4*q4+1]=vv.y; arr[4*q4+2]=vv.z; arr[4*q4+3]=vv.w; }
}

// sigmoid/tanh activation for one dim: preacts arrive pre-scaled by -L2E
// (g gate by -2*L2E). sig = rcp(1+exp2(C)); tanh = 2*sig(2x)-1.
#define ACT(CI,CF,CG,CO, CC, HH) do{ \
  const float iv_ = frcp(1.f + fexp2(CI)); \
  const float fv_ = frcp(1.f + fexp2(CF)); \
  const float gv_ = fmaf(2.f, frcp(1.f + fexp2(CG)), -1.f); \
  const float ov_ = frcp(1.f + fexp2(CO)); \
  CC = fmaf(fv_, CC, iv_*gv_); \
  const float r2_ = frcp(1.f + fexp2((2.f*L2E)*CC)); \
  HH = ov_ * fmaf(-2.f, r2_, 1.f); \
}while(0)

// ---------------------------------------------------------------------------
// Kernel 1 (R12 resubmit: trans spread across 4 SIMDs).
// R11 post-mortem: the LSTM step is transcendental-ISSUE-bound per SIMD
// (~15 cy per wave-wide trans inst). R11 put all 80 trans/step on ONE wave
// -> 1838 cy/step. R12: 4 waves (4 SIMDs), each wave redundantly computes
// ONLY its tile's 4 recurrent + 4 x-proj MFMAs (tile T=wv>>1) and activates
// ONLY its r-pair (wv&1) -> 2 dims/lane = 20 trans/wave/step (the per-CU
// minimum). Exchange: 1x ds_write_b32 (2 f16 dims) + 1 barrier (parity
// double-buffer, statically unrolled x2) + 1x ds_read_b128 (full 32-dim bh)
// per step; ds_read latency hidden under the independent x-proj MFMAs.
// Dim permutation (R11-verified): A row m -> dim 8*(m>>2)+4T+(m&3), so
// D[m=4q+r] = dim 8q+4T+r; lane (q,n) writes dims {8q+4T+2h, +1}.
// Garbage dims 30,31: zero A rows + zero bias -> h=c=0 exactly.
// Fragment layouts (m89/m120-verified):
//   A[m=lane&15][k=(lane>>4)*8+j], B[k=(lane>>4)*8+j][n=lane&15],
//   D[m=(lane>>4)*4+r][n=lane&15].
// ---------------------------------------------------------------------------
extern "C" __global__ void __launch_bounds__(256,1)
lstm_k(const float* __restrict__ input, const float* __restrict__ w_ih,
       const float* __restrict__ w_hh, const float* __restrict__ b_ih,
       const float* __restrict__ b_hh, const float* __restrict__ in_proj_w,
       const float* __restrict__ in_proj_b,
       float* __restrict__ qo, float* __restrict__ ko, float* __restrict__ vo,
       float* __restrict__ ho)
{
  __shared__ __align__(16) _Float16 hb[2*640];     // [parity][n*40 + dim]
  __shared__ __align__(16) float xstf[16*390];     // x: [n][t][6pad]
  const int tid  = threadIdx.x;
  const int wv   = tid >> 6;         // 0..3
  const int lane = tid & 63;
  const int n    = lane & 15;
  const int quad = lane >> 4;
  const int b0   = blockIdx.x * 16;
  const int T    = wv >> 1;          // gate-dim tile (0: dims 8q+0..3, 1: 8q+4..7)
  const int half = wv & 1;           // r-pair within the C quad

  // ---- A-frags for tile T only + bias C-init ----
  f16x8 ah[4], ax[4];
  f32x4 bi[4];
  #pragma unroll
  for (int G=0; G<4; ++G){
    const float sG = (G==2) ? (-2.f*L2E) : (-L2E);
    const int dA = 8*(n>>2) + 4*T + (n&3);         // dim for A row m=n
    const bool rv = (dA < NE);
    const int grow = rv ? (NE*G + dA) : 0;
    #pragma unroll
    for (int j=0;j<8;++j){
      const int k = quad*8 + j;
      ah[G][j] = (rv && k < NE) ? (_Float16)(sG*w_hh[grow*NE + k]) : (_Float16)0;
      ax[G][j] = (rv && quad==0 && j < NIN) ? (_Float16)(sG*w_ih[grow*NIN + j]) : (_Float16)0;
    }
    #pragma unroll
    for (int r=0;r<4;++r){
      const int d = 8*quad + 4*T + r;              // dim for D row m=4q+r
      bi[G][r] = (d < NE) ? sG*(b_ih[NE*G+d] + b_hh[NE*G+d]) : 0.f;
    }
  }
  for (int i=tid; i<640; i+=256) ((float*)hb)[i] = 0.f;
  __syncthreads();

  float c0=0.f, c1=0.f, hs0=0.f, hs1=0.f;
  const int rdo = n*40 + 8*quad;                   // b128 read: dims 8q..8q+7
  const int wro = n*40 + 8*quad + 4*T + 2*half;    // b32 write: my 2 dims
  const float2* x2p = (const float2*)xstf;
  const int xb2 = n*195;
  float2 xA0,xA1,xA2;
  f32x4 Cx[4], Cy[4];

#define LSTM_STEP(CIN, COUT, RB, WB, TT2) do{ \
    const f16x8 bh_ = *(const f16x8*)(hb + (RB) + rdo); \
    union { f16x8 v; h2v h2[4]; } U_; \
    U_.h2[0].x=(_Float16)xA0.x; U_.h2[0].y=(_Float16)xA0.y; \
    U_.h2[1].x=(_Float16)xA1.x; U_.h2[1].y=(_Float16)xA1.y; \
    U_.h2[2].x=(_Float16)xA2.x; U_.h2[2].y=(_Float16)0; \
    U_.h2[3]=(h2v)(_Float16)0; \
    _Pragma("unroll") \
    for (int G=0;G<4;++G) \
      COUT[G] = __builtin_amdgcn_mfma_f32_16x16x32_f16(ax[G], U_.v, bi[G], 0,0,0); \
    { const int t2_=(TT2)&63; const int bb_=xb2+t2_*3; \
      xA0=x2p[bb_]; xA1=x2p[bb_+1]; xA2=x2p[bb_+2]; } \
    f32x4 C_[4]; \
    _Pragma("unroll") \
    for (int G=0;G<4;++G) \
      C_[G] = __builtin_amdgcn_mfma_f32_16x16x32_f16(ah[G], bh_, CIN[G], 0,0,0); \
    if (half==0){ ACT(C_[0][0],C_[1][0],C_[2][0],C_[3][0], c0, hs0); \
                  ACT(C_[0][1],C_[1][1],C_[2][1],C_[3][1], c1, hs1); } \
    else        { ACT(C_[0][2],C_[1][2],C_[2][2],C_[3][2], c0, hs0); \
                  ACT(C_[0][3],C_[1][3],C_[2][3],C_[3][3], c1, hs1); } \
    h2v pp_; pp_.x=(_Float16)hs0; pp_.y=(_Float16)hs1; \
    *(h2v*)(hb + (WB) + wro) = pp_; \
    __syncthreads(); \
  }while(0)

  for (int tc = 0; tc < Tlen; tc += 64) {
    // stage 64 steps x 16 batches x 5 inputs -> padded [n][t][6]
    // (prev chunk's final in-step barrier already drained all xstf reads)
    for (int i4 = tid; i4 < 1280; i4 += 256){
      const int nn = i4/80, e4 = i4%80;
      const float4 v4 = *(const float4*)(input + (size_t)(b0+nn)*(Tlen*NIN) + tc*NIN + e4*4);
      #pragma unroll
      for (int u=0;u<4;++u){
        const int e = e4*4+u;
        xstf[nn*390 + (e/5)*6 + (e%5)] = (&v4.x)[u];
      }
    }
    __syncthreads();
    // prime pipeline: Cx <- x-proj(t=0); xA <- x(t=1)
    {
      const float2 a0=x2p[xb2], a1=x2p[xb2+1], a2=x2p[xb2+2];
      union { f16x8 v; h2v h2[4]; } U;
      U.h2[0].x=(_Float16)a0.x; U.h2[0].y=(_Float16)a0.y;
      U.h2[1].x=(_Float16)a1.x; U.h2[1].y=(_Float16)a1.y;
      U.h2[2].x=(_Float16)a2.x; U.h2[2].y=(_Float16)0;
      U.h2[3]=(h2v)(_Float16)0;
      #pragma unroll
      for (int G=0;G<4;++G)
        Cx[G] = __builtin_amdgcn_mfma_f32_16x16x32_f16(ax[G], U.v, bi[G], 0,0,0);
      xA0 = x2p[xb2+3]; xA1 = x2p[xb2+4]; xA2 = x2p[xb2+5];
    }
    #pragma unroll 1
    for (int tl = 0; tl < 64; tl += 2) {
      LSTM_STEP(Cx, Cy, 0,   640, tl+2);   // even step: read buf0, write buf1
      LSTM_STEP(Cy, Cx, 640, 0,   tl+3);   // odd step : read buf1, write buf0
    }
  }
#undef LSTM_STEP

  // ---- tail: stash fp32 h,c; project q(h), k(c), v(c) ----
  float* hf = xstf;            // [16][36]
  float* cf = xstf + 16*36;
  {
    const int d0 = 8*quad + 4*T + 2*half;
    float2 hv; hv.x=hs0; hv.y=hs1;
    float2 cv; cv.x=c0;  cv.y=c1;
    *(float2*)(&hf[n*36 + d0]) = hv;     // dims 30,31 = exact 0 (harmless)
    *(float2*)(&cf[n*36 + d0]) = cv;
  }
  __syncthreads();
  for (int i = tid; i < 16*NE; i += 256){
    const int nn = i/NE, d = i%NE;
    ho[(size_t)(b0+nn)*NE + d] = hf[nn*36 + d];
  }
  const float QS = 0.31622776601683794f;     // 1/sqrt(10)
  for (int i = tid; i < 90*16; i += 256){
    const int o  = i % 90;
    const int nn = i / 90;
    const float* wrow = in_proj_w + o*NE;
    const float* src  = (o < NE) ? &hf[nn*36] : &cf[nn*36];
    float acc = in_proj_b[o];
    #pragma unroll
    for (int k2=0;k2<NE;k2++) acc = fmaf(wrow[k2], src[k2], acc);
    const int b = b0 + nn;
    if (o < 30)      { qo[(o/10)*B10 + b*10 + (o%10)] = acc * QS; }
    else if (o < 60) { const int u=o-30; ko[(u/10)*B10 + b*10 + (u%10)] = acc; }
    else             { const int u=o-60; vo[(u/10)*B10 + b*10 + (u%10)] = acc; }
  }
}

// ---------------------------------------------------------------------------
// Kernel 2 (R10: cooperative LDS staging): flash attention partials.
// Thread = query. grid (16 qblocks, 3 heads, NS), block 256.
// ---------------------------------------------------------------------------
extern "C" __global__ void __launch_bounds__(256)
attn_part(const float* __restrict__ q, const float* __restrict__ k,
          const float* __restrict__ v, float* __restrict__ part, int nkeys)
{
  __shared__ __align__(16) float kst[640];   // 64 keys x 10
  __shared__ __align__(16) float vst[640];
  const int t    = threadIdx.x;
  const int qr   = blockIdx.x*256 + t;
  const int head = blockIdx.y;
  const int ks   = blockIdx.z;
  const float* kh = k + (size_t)head*B10;
  const float* vh = v + (size_t)head*B10;
  float qreg[10];
  {
    const float2* qp = (const float2*)(q + (size_t)head*B10 + (size_t)qr*10);
    #pragma unroll
    for (int i=0;i<5;i++){ float2 t2=qp[i]; qreg[2*i]=t2.x; qreg[2*i+1]=t2.y; }
  }
  float m = -INFINITY, l = 0.f, acc[10];
  #pragma unroll
  for (int d=0;d<10;d++) acc[d]=0.f;

  const int k0 = ks * nkeys;
  const int nt = nkeys >> 6;           // 64-key tiles
  #pragma unroll 1
  for (int ti=0; ti<nt; ++ti){
    const int kt0 = k0 + (ti<<6);
    __syncthreads();                   // previous tile's reads complete
    {
      const float4* ksrc = (const float4*)(kh + (size_t)kt0*10);
      const float4* vsrc = (const float4*)(vh + (size_t)kt0*10);
      for (int i=t; i<320; i+=256){
        if (i < 160) ((float4*)kst)[i]     = ksrc[i];
        else         ((float4*)vst)[i-160] = vsrc[i-160];
      }
    }
    __syncthreads();                   // staging visible
    #pragma unroll 1
    for (int c8=0; c8<64; c8+=8){
      float s[8];
      #pragma unroll
      for (int u=0;u<8;u++){
        const float2* kp = (const float2*)(kst + (c8+u)*10);
        float sv = 0.f;
        #pragma unroll
        for (int i=0;i<5;i++){ float2 kk=kp[i]; sv=fmaf(qreg[2*i],kk.x,sv); sv=fmaf(qreg[2*i+1],kk.y,sv); }
        s[u]=sv;
      }
      float mc = s[0];
      #pragma unroll
      for (int u=1;u<8;u++) mc = fmaxf(mc, s[u]);
      const float mnew = fmaxf(m, mc);
      const float corr = fexp2(L2E*(m - mnew));   // m=-inf first chunk -> 0
      l *= corr;
      #pragma unroll
      for (int d=0;d<10;d++) acc[d]*=corr;
      #pragma unroll
      for (int u=0;u<8;u++){
        const float p = fexp2(L2E*(s[u]-mnew));
        l += p;
        const float2* vp = (const float2*)(vst + (c8+u)*10);
        #pragma unroll
        for (int i=0;i<5;i++){ float2 vv=vp[i]; acc[2*i]=fmaf(p,vv.x,acc[2*i]); acc[2*i+1]=fmaf(p,vv.y,acc[2*i+1]); }
      }
      m = mnew;
    }
  }
  float* pp = part + ((size_t)(head*Bsz + qr)*gridDim.z + ks)*12;
  pp[0]=m; pp[1]=l;
  #pragma unroll
  for (int d=0;d<10;d++) pp[2+d]=acc[d];
}

// ---------------------------------------------------------------------------
// Kernel 3 (R10: LDS weights): fused merge + out_proj + LN + MLP + LN + head.
// One wave per row. Weight matrices staged to LDS once per block.
// ---------------------------------------------------------------------------
extern "C" __global__ void __launch_bounds__(256)
tail_k(const float* __restrict__ part, int ns, const float* __restrict__ hn,
       const float* __restrict__ out_proj_w, const float* __restrict__ out_proj_b,
       const float* __restrict__ fc1_w, const float* __restrict__ fc1_b,
       const float* __restrict__ fc2_w, const float* __restrict__ fc2_b,
       const float* __restrict__ ln_g, const float* __restrict__ ln_b,
       const float* __restrict__ out_w, const float* __restrict__ out_b,
       float* __restrict__ out)
{
  __shared__ __align__(16) float buf[4][32];
  __shared__ float wl[2880];   // [0]=out_proj_w 900, [900]=fc1_w, [1800]=fc2_w, [2700]=out_w 90
  const int tidb = threadIdx.x;
  for (int i=tidb;i<900;i+=256) wl[i]       = out_proj_w[i];
  for (int i=tidb;i<900;i+=256) wl[900+i]   = fc1_w[i];
  for (int i=tidb;i<900;i+=256) wl[1800+i]  = fc2_w[i];
  if (tidb < 90) wl[2700+tidb] = out_w[tidb];
  const int wave = tidb >> 6;
  const int lane = tidb & 63;
  const int b = blockIdx.x*4 + wave;
  const bool act = (lane < NE);
  if (lane < 32) buf[wave][lane] = 0.f;
  __syncthreads();
  if (act) {
    const int head = lane/10, dd = lane%10;
    const float* p = part + ((size_t)(head*Bsz + b)*ns)*12;
    float M = -INFINITY, L = 0.f, O = 0.f;
    for (int i=0;i<ns;i++){
      const float mi = p[i*12], li = p[i*12+1], ai = p[i*12+2+dd];
      const float Mn = fmaxf(M, mi);
      const float cw = fexp2(L2E*(M - Mn));
      const float wi = fexp2(L2E*(mi - Mn));
      L = fmaf(li, wi, L*cw);
      O = fmaf(ai, wi, O*cw);
      M = Mn;
    }
    buf[wave][lane] = O / L;
  }
  __builtin_amdgcn_wave_barrier();
  float arr[32];
  loadarr32(arr, &buf[wave][0]);
  const float hv = act ? hn[b*NE+lane] : 0.f;
  float x = 0.f;
  if (act) {
    float a = out_proj_b[lane];
    #pragma unroll
    for (int k2=0;k2<NE;k2++) a = fmaf(wl[lane*NE+k2], arr[k2], a);
    x = a + hv;                       // attn_out + h_n
  }
  // LN1
  __builtin_amdgcn_wave_barrier();
  if (act) buf[wave][lane] = x;
  __builtin_amdgcn_wave_barrier();
  loadarr32(arr, &buf[wave][0]);
  float s1=0.f, s2=0.f;
  #pragma unroll
  for (int k2=0;k2<32;k2++){ s1+=arr[k2]; s2=fmaf(arr[k2],arr[k2],s2); }
  float mu = s1*(1.f/30.f);
  float var = s2*(1.f/30.f) - mu*mu;
  float rs = rsqrtf(var + 1e-5f);
  float x1 = 0.f;
  if (act) x1 = fmaf((x-mu)*rs, ln_g[lane], ln_b[lane]);
  // fc1 + exact GELU
  __builtin_amdgcn_wave_barrier();
  if (act) buf[wave][lane] = x1;
  __builtin_amdgcn_wave_barrier();
  loadarr32(arr, &buf[wave][0]);
  float gv = 0.f;
  if (act) {
    float a = fc1_b[lane];
    #pragma unroll
    for (int k2=0;k2<NE;k2++) a = fmaf(wl[900+lane*NE+k2], arr[k2], a);
    gv = 0.5f*a*(1.f + erff(a*0.70710678118654752f));
  }
  // fc2
  __builtin_amdgcn_wave_barrier();
  if (act) buf[wave][lane] = gv;
  __builtin_amdgcn_wave_barrier();
  loadarr32(arr, &buf[wave][0]);
  float y = 0.f;
  if (act) {
    float a = fc2_b[lane];
    #pragma unroll
    for (int k2=0;k2<NE;k2++) a = fmaf(wl[1800+lane*NE+k2], arr[k2], a);
    y = x1 + a;                        // residual x1 + fc
  }
  // LN2
  __builtin_amdgcn_wave_barrier();
  if (act) buf[wave][lane] = y;
  __builtin_amdgcn_wave_barrier();
  loadarr32(arr, &buf[wave][0]);
  s1=0.f; s2=0.f;
  #pragma unroll
  for (int k2=0;k2<32;k2++){ s1+=arr[k2]; s2=fmaf(arr[k2],arr[k2],s2); }
  mu = s1*(1.f/30.f);
  var = s2*(1.f/30.f) - mu*mu;
  rs = rsqrtf(var + 1e-5f);
  float x2 = 0.f;
  if (act) x2 = fmaf((y-mu)*rs, ln_g[lane], ln_b[lane]);
  // head: [3,30]
  __builtin_amdgcn_wave_barrier();
  if (act) buf[wave][lane] = x2;
  __builtin_amdgcn_wave_barrier();
  loadarr32(arr, &buf[wave][0]);
  if (lane < 3) {
    float a = out_b[lane];
    #pragma unroll
    for (int k2=0;k2<NE;k2++) a = fmaf(wl[2700+lane*NE+k2], arr[k2], a);
    out[b*3 + lane] = a;
  }
}

extern "C" void kernel_launch(void* const* d_in, const int* in_sizes, int n_in,
                              void* d_out, int out_size, void* d_ws, size_t ws_size,
                              hipStream_t stream)
{
  const float* input      = (const float*)d_in[0];
  const float* w_ih       = (const float*)d_in[1];
  const float* w_hh       = (const float*)d_in[2];
  const float* b_ih       = (const float*)d_in[3];
  const float* b_hh       = (const float*)d_in[4];
  const float* in_proj_w  = (const float*)d_in[5];
  const float* in_proj_b  = (const float*)d_in[6];
  const float* out_proj_w = (const float*)d_in[7];
  const float* out_proj_b = (const float*)d_in[8];
  const float* fc1_w      = (const float*)d_in[9];
  const float* fc1_b      = (const float*)d_in[10];
  const float* fc2_w      = (const float*)d_in[11];
  const float* fc2_b      = (const float*)d_in[12];
  const float* ln_g       = (const float*)d_in[13];
  const float* ln_b       = (const float*)d_in[14];
  const float* out_w      = (const float*)d_in[15];
  const float* out_b      = (const float*)d_in[16];

  float* ws = (float*)d_ws;
  float* qo   = ws;                 // [3][4096][10]
  float* ko   = ws + 122880;        // [3][4096][10]
  float* vo   = ws + 245760;        // [3][4096][10]
  float* hn   = ws + 368640;        // [4096][30]
  float* part = ws + 491520;        // [3][4096][NS][12]

  const size_t need16 = ((size_t)491520 + (size_t)3*4096*16*12) * 4;
  const int NS = (ws_size >= need16) ? 16 : 8;

  lstm_k<<<Bsz/16, 256, 0, stream>>>(input, w_ih, w_hh, b_ih, b_hh,
                                     in_proj_w, in_proj_b, qo, ko, vo, hn);
  attn_part<<<dim3(Bsz/256, 3, NS), 256, 0, stream>>>(qo, ko, vo, part, Bsz/NS);
  tail_k<<<Bsz/4, 256, 0, stream>>>(part, NS, hn, out_proj_w, out_proj_b,
                                    fc1_w, fc1_b, fc2_w, fc2_b,
                                    ln_g, ln_b, out_w, out_b, (float*)d_out);
}

// Round 4
// 318.302 us; speedup vs baseline: 1.6351x; 1.1328x over previous
//
#include <hip/hip_runtime.h>
#include <math.h>

// Problem constants
#define Bsz  4096
#define Tlen 512
#define NE   30
#define NIN  5
#define HD10 10
#define B10  (Bsz*HD10)   // per-head plane: 40960 floats

typedef _Float16 h2v  __attribute__((ext_vector_type(2)));
typedef _Float16 f16x8 __attribute__((ext_vector_type(8)));
typedef float    f32x4 __attribute__((ext_vector_type(4)));

__device__ __forceinline__ float fexp2(float x){ return __builtin_amdgcn_exp2f(x); }
__device__ __forceinline__ float frcp (float x){ return __builtin_amdgcn_rcpf(x); }
#define L2E 1.4426950408889634f

__device__ __forceinline__ void loadarr32(float arr[32], const float* bufrow){
  const float4* p4 = (const float4*)bufrow;
  #pragma unroll
  for (int q4=0;q4<8;q4++){ float4 vv=p4[q4]; arr[4*q4]=vv.x; arr[4*q4+1]=vv.y; arr[4*q4+2]=vv.z; arr[4*q4+3]=vv.w; }
}

// ---------------------------------------------------------------------------
// Kernel 1 (R13: 8-wave / 1-dim-per-lane / merged-rcp / packed-f16 x).
// Model (fit from R8/R11/R12): wave64 trans inst ~16 issue cy (4-wide unit).
// R12 = 20 trans-insts/SIMD (320 cy) + ~140 other VALU + ~560 exposed stalls
// (1 wave/SIMD hides nothing). R13:
//  - ACT rcp-merge: i*g=(2-G2)*rcp(B*G2), o*tanh=(E2-2)*rcp(D*E2):
//    10 -> 8 trans per dim (5 exp2 + 3 rcp).
//  - 8 waves (2/SIMD): each wave activates 1 dim/lane; same total trans
//    issue, but co-resident waves hide each other's LDS/MFMA/barrier stalls.
//  - x staged as f16 pre-packed [x0..x4,0,0,0] per (n,t): one ds_read_b128
//    replaces 3 ds_read_b64 + 5 cvt + packs per step. Stride 520 f16
//    (2-way bank alias = free).
//  - per-wave A-row permutation dim = 8q + ((wv + r)&7): the wave's owned
//    dim sits at r=0 -> static C_[G][0] extraction, no branches.
// Exchange per step: 1 ds_read_b128 (bh) + 1 ds_write_b16 + 1 barrier
// (parity double-buffer, unrolled x2).
// Garbage dims 30,31 (waves 6,7 at q=3): zero A rows + zero bias -> preact
// 0 -> c=h=0 exactly; k-columns 30,31 of ah also zeroed.
// Fragment layouts (m89/m120-verified):
//   A[m=lane&15][k=(lane>>4)*8+j], B[k=(lane>>4)*8+j][n=lane&15],
//   D[m=(lane>>4)*4+r][n=lane&15].
// ---------------------------------------------------------------------------
#define XSTR 520   // f16 stride per batch in xh (padded: 260 dw % 32 = 4)

extern "C" __global__ void __launch_bounds__(512,1)
lstm_k(const float* __restrict__ input, const float* __restrict__ w_ih,
       const float* __restrict__ w_hh, const float* __restrict__ b_ih,
       const float* __restrict__ b_hh, const float* __restrict__ in_proj_w,
       const float* __restrict__ in_proj_b,
       float* __restrict__ qo, float* __restrict__ ko, float* __restrict__ vo,
       float* __restrict__ ho)
{
  __shared__ __align__(16) _Float16 hb[2*640];     // [parity][n*40 + dim]
  __shared__ __align__(16) _Float16 xh[16*XSTR];   // [n][t][8] f16 packed
  const int tid  = threadIdx.x;
  const int wv   = __builtin_amdgcn_readfirstlane(tid >> 6);   // 0..7 (SGPR)
  const int lane = tid & 63;
  const int n    = lane & 15;
  const int quad = lane >> 4;
  const int b0   = blockIdx.x * 16;

  // ---- A-frags with per-wave row permutation: row m -> dim 8*(m>>2) + ((wv+(m&3))&7)
  f16x8 ah[4], ax[4];
  f32x4 bi[4];
  #pragma unroll
  for (int G=0; G<4; ++G){
    const float sG = (G==2) ? (-2.f*L2E) : (-L2E);   // g gate: x2 scale for tanh
    const int dA = 8*(n>>2) + ((wv + (n&3)) & 7);    // dim for A row m=n
    const bool rv = (dA < NE);
    const int grow = rv ? (NE*G + dA) : 0;
    #pragma unroll
    for (int j=0;j<8;++j){
      const int k = quad*8 + j;
      ah[G][j] = (rv && k < NE) ? (_Float16)(sG*w_hh[grow*NE + k]) : (_Float16)0;
      ax[G][j] = (rv && quad==0 && j < NIN) ? (_Float16)(sG*w_ih[grow*NIN + j]) : (_Float16)0;
    }
    #pragma unroll
    for (int r=0;r<4;++r){
      const int d = 8*quad + ((wv + r) & 7);         // dim for D row m=4q+r
      bi[G][r] = (d < NE) ? sG*(b_ih[NE*G+d] + b_hh[NE*G+d]) : 0.f;
    }
  }
  // zero h double-buffer and xh (slots 5..7 stay 0 forever)
  for (int i=tid; i<640; i+=512) ((float*)hb)[i] = 0.f;
  for (int i=tid; i<16*XSTR; i+=512) xh[i] = (_Float16)0;
  __syncthreads();

  float cc=0.f, hh=0.f;
  const int rdo  = n*40 + 8*quad;          // b128 read: dims 8q..8q+7 (f16 idx)
  const int wro  = n*40 + 8*quad + wv;     // b16 write: my dim
  const int xoff = n*XSTR;
  f16x8 xB;
  f32x4 Cx[4], Cy[4];

#define LSTM_STEP(CIN, COUT, RB, WB, TT2) do{ \
    const f16x8 bh_ = *(const f16x8*)(hb + (RB) + rdo); \
    _Pragma("unroll") \
    for (int G=0;G<4;++G) \
      COUT[G] = __builtin_amdgcn_mfma_f32_16x16x32_f16(ax[G], xB, bi[G], 0,0,0); \
    xB = *(const f16x8*)(xh + xoff + ((TT2)&63)*8); \
    f32x4 C_[4]; \
    _Pragma("unroll") \
    for (int G=0;G<4;++G) \
      C_[G] = __builtin_amdgcn_mfma_f32_16x16x32_f16(ah[G], bh_, CIN[G], 0,0,0); \
    /* ACT (r=0 row = this wave's dim): 5 exp2 + 3 rcp */ \
    const float ei=fexp2(C_[0][0]), ef=fexp2(C_[1][0]); \
    const float eg=fexp2(C_[2][0]), eo=fexp2(C_[3][0]); \
    const float Af=1.f+ef, Bi_=1.f+ei, G2=1.f+eg; \
    cc = cc*frcp(Af) + (2.f-G2)*frcp(Bi_*G2); \
    const float e2=fexp2((2.f*L2E)*cc); \
    const float E2=1.f+e2; \
    hh = (E2-2.f)*frcp((1.f+eo)*E2); \
    hb[(WB) + wro] = (_Float16)hh; \
    __syncthreads(); \
  }while(0)

  for (int tc = 0; tc < Tlen; tc += 64) {
    // stage 64 steps x 16 batches x 5 inputs -> f16 packed [n][t][8]
    // (prev chunk's final in-step barrier drained all xh reads)
    for (int i4 = tid; i4 < 1280; i4 += 512){
      const int nn = i4/80, e4 = i4%80;
      const float4 v4 = *(const float4*)(input + (size_t)(b0+nn)*(Tlen*NIN) + tc*NIN + e4*4);
      #pragma unroll
      for (int u=0;u<4;++u){
        const int e = e4*4+u;                        // 0..319 = t*5+c
        xh[nn*XSTR + (e/5)*8 + (e%5)] = (_Float16)((&v4.x)[u]);
      }
    }
    __syncthreads();
    // prime: Cx <- x-proj(t=0); xB <- x(1)
    {
      const f16x8 x0 = *(const f16x8*)(xh + xoff);
      #pragma unroll
      for (int G=0;G<4;++G)
        Cx[G] = __builtin_amdgcn_mfma_f32_16x16x32_f16(ax[G], x0, bi[G], 0,0,0);
      xB = *(const f16x8*)(xh + xoff + 8);
    }
    #pragma unroll 1
    for (int tl = 0; tl < 64; tl += 2) {
      LSTM_STEP(Cx, Cy, 0,   640, tl+2);   // even: read buf0, write buf1
      LSTM_STEP(Cy, Cx, 640, 0,   tl+3);   // odd : read buf1, write buf0
    }
  }
#undef LSTM_STEP

  // ---- tail: stash fp32 h,c (reuse xh as f32 scratch); project q,k,v ----
  float* hf = (float*)xh;      // [16][36]
  float* cf = hf + 16*36;
  {
    hf[n*36 + 8*quad + wv] = hh;   // dims 30,31 = exact 0 (harmless)
    cf[n*36 + 8*quad + wv] = cc;
  }
  __syncthreads();
  for (int i = tid; i < 16*NE; i += 512){
    const int nn = i/NE, d = i%NE;
    ho[(size_t)(b0+nn)*NE + d] = hf[nn*36 + d];
  }
  const float QS = 0.31622776601683794f;     // 1/sqrt(10)
  for (int i = tid; i < 90*16; i += 512){
    const int o  = i % 90;
    const int nn = i / 90;
    const float* wrow = in_proj_w + o*NE;
    const float* src  = (o < NE) ? &hf[nn*36] : &cf[nn*36];
    float acc = in_proj_b[o];
    #pragma unroll
    for (int k2=0;k2<NE;k2++) acc = fmaf(wrow[k2], src[k2], acc);
    const int b = b0 + nn;
    if (o < 30)      { qo[(o/10)*B10 + b*10 + (o%10)] = acc * QS; }
    else if (o < 60) { const int u=o-30; ko[(u/10)*B10 + b*10 + (u%10)] = acc; }
    else             { const int u=o-60; vo[(u/10)*B10 + b*10 + (u%10)] = acc; }
  }
}

// ---------------------------------------------------------------------------
// Kernel 2 (R10: cooperative LDS staging): flash attention partials.
// Thread = query. grid (16 qblocks, 3 heads, NS), block 256.
// ---------------------------------------------------------------------------
extern "C" __global__ void __launch_bounds__(256)
attn_part(const float* __restrict__ q, const float* __restrict__ k,
          const float* __restrict__ v, float* __restrict__ part, int nkeys)
{
  __shared__ __align__(16) float kst[640];   // 64 keys x 10
  __shared__ __align__(16) float vst[640];
  const int t    = threadIdx.x;
  const int qr   = blockIdx.x*256 + t;
  const int head = blockIdx.y;
  const int ks   = blockIdx.z;
  const float* kh = k + (size_t)head*B10;
  const float* vh = v + (size_t)head*B10;
  float qreg[10];
  {
    const float2* qp = (const float2*)(q + (size_t)head*B10 + (size_t)qr*10);
    #pragma unroll
    for (int i=0;i<5;i++){ float2 t2=qp[i]; qreg[2*i]=t2.x; qreg[2*i+1]=t2.y; }
  }
  float m = -INFINITY, l = 0.f, acc[10];
  #pragma unroll
  for (int d=0;d<10;d++) acc[d]=0.f;

  const int k0 = ks * nkeys;
  const int nt = nkeys >> 6;           // 64-key tiles
  #pragma unroll 1
  for (int ti=0; ti<nt; ++ti){
    const int kt0 = k0 + (ti<<6);
    __syncthreads();                   // previous tile's reads complete
    {
      const float4* ksrc = (const float4*)(kh + (size_t)kt0*10);
      const float4* vsrc = (const float4*)(vh + (size_t)kt0*10);
      for (int i=t; i<320; i+=256){
        if (i < 160) ((float4*)kst)[i]     = ksrc[i];
        else         ((float4*)vst)[i-160] = vsrc[i-160];
      }
    }
    __syncthreads();                   // staging visible
    #pragma unroll 1
    for (int c8=0; c8<64; c8+=8){
      float s[8];
      #pragma unroll
      for (int u=0;u<8;u++){
        const float2* kp = (const float2*)(kst + (c8+u)*10);
        float sv = 0.f;
        #pragma unroll
        for (int i=0;i<5;i++){ float2 kk=kp[i]; sv=fmaf(qreg[2*i],kk.x,sv); sv=fmaf(qreg[2*i+1],kk.y,sv); }
        s[u]=sv;
      }
      float mc = s[0];
      #pragma unroll
      for (int u=1;u<8;u++) mc = fmaxf(mc, s[u]);
      const float mnew = fmaxf(m, mc);
      const float corr = fexp2(L2E*(m - mnew));   // m=-inf first chunk -> 0
      l *= corr;
      #pragma unroll
      for (int d=0;d<10;d++) acc[d]*=corr;
      #pragma unroll
      for (int u=0;u<8;u++){
        const float p = fexp2(L2E*(s[u]-mnew));
        l += p;
        const float2* vp = (const float2*)(vst + (c8+u)*10);
        #pragma unroll
        for (int i=0;i<5;i++){ float2 vv=vp[i]; acc[2*i]=fmaf(p,vv.x,acc[2*i]); acc[2*i+1]=fmaf(p,vv.y,acc[2*i+1]); }
      }
      m = mnew;
    }
  }
  float* pp = part + ((size_t)(head*Bsz + qr)*gridDim.z + ks)*12;
  pp[0]=m; pp[1]=l;
  #pragma unroll
  for (int d=0;d<10;d++) pp[2+d]=acc[d];
}

// ---------------------------------------------------------------------------
// Kernel 3 (R10: LDS weights): fused merge + out_proj + LN + MLP + LN + head.
// One wave per row. Weight matrices staged to LDS once per block.
// ---------------------------------------------------------------------------
extern "C" __global__ void __launch_bounds__(256)
tail_k(const float* __restrict__ part, int ns, const float* __restrict__ hn,
       const float* __restrict__ out_proj_w, const float* __restrict__ out_proj_b,
       const float* __restrict__ fc1_w, const float* __restrict__ fc1_b,
       const float* __restrict__ fc2_w, const float* __restrict__ fc2_b,
       const float* __restrict__ ln_g, const float* __restrict__ ln_b,
       const float* __restrict__ out_w, const float* __restrict__ out_b,
       float* __restrict__ out)
{
  __shared__ __align__(16) float buf[4][32];
  __shared__ float wl[2880];   // [0]=out_proj_w 900, [900]=fc1_w, [1800]=fc2_w, [2700]=out_w 90
  const int tidb = threadIdx.x;
  for (int i=tidb;i<900;i+=256) wl[i]       = out_proj_w[i];
  for (int i=tidb;i<900;i+=256) wl[900+i]   = fc1_w[i];
  for (int i=tidb;i<900;i+=256) wl[1800+i]  = fc2_w[i];
  if (tidb < 90) wl[2700+tidb] = out_w[tidb];
  const int wave = tidb >> 6;
  const int lane = tidb & 63;
  const int b = blockIdx.x*4 + wave;
  const bool act = (lane < NE);
  if (lane < 32) buf[wave][lane] = 0.f;
  __syncthreads();
  if (act) {
    const int head = lane/10, dd = lane%10;
    const float* p = part + ((size_t)(head*Bsz + b)*ns)*12;
    float M = -INFINITY, L = 0.f, O = 0.f;
    for (int i=0;i<ns;i++){
      const float mi = p[i*12], li = p[i*12+1], ai = p[i*12+2+dd];
      const float Mn = fmaxf(M, mi);
      const float cw = fexp2(L2E*(M - Mn));
      const float wi = fexp2(L2E*(mi - Mn));
      L = fmaf(li, wi, L*cw);
      O = fmaf(ai, wi, O*cw);
      M = Mn;
    }
    buf[wave][lane] = O / L;
  }
  __builtin_amdgcn_wave_barrier();
  float arr[32];
  loadarr32(arr, &buf[wave][0]);
  const float hv = act ? hn[b*NE+lane] : 0.f;
  float x = 0.f;
  if (act) {
    float a = out_proj_b[lane];
    #pragma unroll
    for (int k2=0;k2<NE;k2++) a = fmaf(wl[lane*NE+k2], arr[k2], a);
    x = a + hv;                       // attn_out + h_n
  }
  // LN1
  __builtin_amdgcn_wave_barrier();
  if (act) buf[wave][lane] = x;
  __builtin_amdgcn_wave_barrier();
  loadarr32(arr, &buf[wave][0]);
  float s1=0.f, s2=0.f;
  #pragma unroll
  for (int k2=0;k2<32;k2++){ s1+=arr[k2]; s2=fmaf(arr[k2],arr[k2],s2); }
  float mu = s1*(1.f/30.f);
  float var = s2*(1.f/30.f) - mu*mu;
  float rs = rsqrtf(var + 1e-5f);
  float x1 = 0.f;
  if (act) x1 = fmaf((x-mu)*rs, ln_g[lane], ln_b[lane]);
  // fc1 + exact GELU
  __builtin_amdgcn_wave_barrier();
  if (act) buf[wave][lane] = x1;
  __builtin_amdgcn_wave_barrier();
  loadarr32(arr, &buf[wave][0]);
  float gv = 0.f;
  if (act) {
    float a = fc1_b[lane];
    #pragma unroll
    for (int k2=0;k2<NE;k2++) a = fmaf(wl[900+lane*NE+k2], arr[k2], a);
    gv = 0.5f*a*(1.f + erff(a*0.70710678118654752f));
  }
  // fc2
  __builtin_amdgcn_wave_barrier();
  if (act) buf[wave][lane] = gv;
  __builtin_amdgcn_wave_barrier();
  loadarr32(arr, &buf[wave][0]);
  float y = 0.f;
  if (act) {
    float a = fc2_b[lane];
    #pragma unroll
    for (int k2=0;k2<NE;k2++) a = fmaf(wl[1800+lane*NE+k2], arr[k2], a);
    y = x1 + a;                        // residual x1 + fc
  }
  // LN2
  __builtin_amdgcn_wave_barrier();
  if (act) buf[wave][lane] = y;
  __builtin_amdgcn_wave_barrier();
  loadarr32(arr, &buf[wave][0]);
  s1=0.f; s2=0.f;
  #pragma unroll
  for (int k2=0;k2<32;k2++){ s1+=arr[k2]; s2=fmaf(arr[k2],arr[k2],s2); }
  mu = s1*(1.f/30.f);
  var = s2*(1.f/30.f) - mu*mu;
  rs = rsqrtf(var + 1e-5f);
  float x2 = 0.f;
  if (act) x2 = fmaf((y-mu)*rs, ln_g[lane], ln_b[lane]);
  // head: [3,30]
  __builtin_amdgcn_wave_barrier();
  if (act) buf[wave][lane] = x2;
  __builtin_amdgcn_wave_barrier();
  loadarr32(arr, &buf[wave][0]);
  if (lane < 3) {
    float a = out_b[lane];
    #pragma unroll
    for (int k2=0;k2<NE;k2++) a = fmaf(wl[2700+lane*NE+k2], arr[k2], a);
    out[b*3 + lane] = a;
  }
}

extern "C" void kernel_launch(void* const* d_in, const int* in_sizes, int n_in,
                              void* d_out, int out_size, void* d_ws, size_t ws_size,
                              hipStream_t stream)
{
  const float* input      = (const float*)d_in[0];
  const float* w_ih       = (const float*)d_in[1];
  const float* w_hh       = (const float*)d_in[2];
  const float* b_ih       = (const float*)d_in[3];
  const float* b_hh       = (const float*)d_in[4];
  const float* in_proj_w  = (const float*)d_in[5];
  const float* in_proj_b  = (const float*)d_in[6];
  const float* out_proj_w = (const float*)d_in[7];
  const float* out_proj_b = (const float*)d_in[8];
  const float* fc1_w      = (const float*)d_in[9];
  const float* fc1_b      = (const float*)d_in[10];
  const float* fc2_w      = (const float*)d_in[11];
  const float* fc2_b      = (const float*)d_in[12];
  const float* ln_g       = (const float*)d_in[13];
  const float* ln_b       = (const float*)d_in[14];
  const float* out_w      = (const float*)d_in[15];
  const float* out_b      = (const float*)d_in[16];

  float* ws = (float*)d_ws;
  float* qo   = ws;                 // [3][4096][10]
  float* ko   = ws + 122880;        // [3][4096][10]
  float* vo   = ws + 245760;        // [3][4096][10]
  float* hn   = ws + 368640;        // [4096][30]
  float* part = ws + 491520;        // [3][4096][NS][12]

  const size_t need16 = ((size_t)491520 + (size_t)3*4096*16*12) * 4;
  const int NS = (ws_size >= need16) ? 16 : 8;

  lstm_k<<<Bsz/16, 512, 0, stream>>>(input, w_ih, w_hh, b_ih, b_hh,
                                     in_proj_w, in_proj_b, qo, ko, vo, hn);
  attn_part<<<dim3(Bsz/256, 3, NS), 256, 0, stream>>>(qo, ko, vo, part, Bsz/NS);
  tail_k<<<Bsz/4, 256, 0, stream>>>(part, NS, hn, out_proj_w, out_proj_b,
                                    fc1_w, fc1_b, fc2_w, fc2_b,
                                    ln_g, ln_b, out_w, out_b, (float*)d_out);
}

// Round 5
// 289.448 us; speedup vs baseline: 1.7981x; 1.0997x over previous
//
#include <hip/hip_runtime.h>
#include <math.h>

// Problem constants
#define Bsz  4096
#define Tlen 512
#define NE   30
#define NIN  5
#define HD10 10
#define B10  (Bsz*HD10)   // per-head plane: 40960 floats

typedef _Float16 h2v  __attribute__((ext_vector_type(2)));
typedef _Float16 f16x8 __attribute__((ext_vector_type(8)));
typedef float    f32x4 __attribute__((ext_vector_type(4)));

__device__ __forceinline__ float fexp2(float x){ return __builtin_amdgcn_exp2f(x); }
__device__ __forceinline__ float frcp (float x){ return __builtin_amdgcn_rcpf(x); }
#define L2E 1.4426950408889634f

__device__ __forceinline__ void loadarr32(float arr[32], const float* bufrow){
  const float4* p4 = (const float4*)bufrow;
  #pragma unroll
  for (int q4=0;q4<8;q4++){ float4 vv=p4[q4]; arr[4*q4]=vv.x; arr[4*q4+1]=vv.y; arr[4*q4+2]=vv.z; arr[4*q4+3]=vv.w; }
}

// ---------------------------------------------------------------------------
// Kernel 1 (R14: gate-packed MFMA rows -- 2 MFMA/wave/step).
// R13 post-mortem: MfmaUtil 31% -> matrix pipe ~310 cy/step/SIMD (16 MFMA @
// ~19.4 cy/SIMD each) co-dominant with the 256-cy trans floor. R13 wasted
// 12/16 D rows (one gate per MFMA). R14 packs row m=4*qm+r as
// (dim 8*qm+wv, gate r): ONE recurrent MFMA gives lane (q,n) all 4 gate
// preacts for its dim 8q+wv in C[0..3]; same for x-proj. 8->2 MFMA/wave/step.
// Trans (8/lane/step: 5 exp2 + 3 rcp merged) is the remaining floor:
// 2 waves/SIMD x 8 = 16 insts x ~16 cy = 256 cy/SIMD/step.
// Exchange per step: 1 ds_read_b128 (bh) + x b128 broadcast + 1 ds_write_b16
// + 1 barrier (parity double-buffer, unrolled x2).
// Garbage dims 30,31 (qm=3, wv=6/7): zero A rows + zero bias -> preact 0 ->
// cc decays from 0 (stays 0), hh=(2-2)*rcp=0 exactly.
// Fragment layouts (m89/m120-verified):
//   A[m=lane&15][k=(lane>>4)*8+j], B[k=(lane>>4)*8+j][n=lane&15],
//   D[m=(lane>>4)*4+r][n=lane&15].
// ---------------------------------------------------------------------------
#define XSTR 520   // f16 stride per batch in xh (padded)

extern "C" __global__ void __launch_bounds__(512,1)
lstm_k(const float* __restrict__ input, const float* __restrict__ w_ih,
       const float* __restrict__ w_hh, const float* __restrict__ b_ih,
       const float* __restrict__ b_hh, const float* __restrict__ in_proj_w,
       const float* __restrict__ in_proj_b,
       float* __restrict__ qo, float* __restrict__ ko, float* __restrict__ vo,
       float* __restrict__ ho)
{
  __shared__ __align__(16) _Float16 hb[2*640];     // [parity][n*40 + dim]
  __shared__ __align__(16) _Float16 xh[16*XSTR];   // [n][t][8] f16 packed
  const int tid  = threadIdx.x;
  const int wv   = __builtin_amdgcn_readfirstlane(tid >> 6);   // 0..7 (SGPR)
  const int lane = tid & 63;
  const int n    = lane & 15;
  const int quad = lane >> 4;
  const int b0   = blockIdx.x * 16;

  // ---- gate-packed A-frags: A row m = (dim 8*(m>>2)+wv, gate m&3) ----
  f16x8 ah, ax;
  f32x4 bi;
  {
    const int r  = n & 3;               // gate for A row m=n
    const int qm = n >> 2;
    const int dA = 8*qm + wv;           // dim for A row m=n
    const float sG = (r==2) ? (-2.f*L2E) : (-L2E);   // g gate: x2 scale for tanh
    const bool rv = (dA < NE);
    const int grow = rv ? (r*NE + dA) : 0;
    #pragma unroll
    for (int j=0;j<8;++j){
      const int k = quad*8 + j;
      ah[j] = (rv && k < NE) ? (_Float16)(sG*w_hh[grow*NE + k]) : (_Float16)0;
      ax[j] = (rv && quad==0 && j < NIN) ? (_Float16)(sG*w_ih[grow*NIN + j]) : (_Float16)0;
    }
    const int d = 8*quad + wv;          // this lane's dim (D row 4q+rr = gate rr)
    #pragma unroll
    for (int rr=0;rr<4;++rr){
      const float sR = (rr==2) ? (-2.f*L2E) : (-L2E);
      bi[rr] = (d < NE) ? sR*(b_ih[rr*NE+d] + b_hh[rr*NE+d]) : 0.f;
    }
  }
  // zero h double-buffer and xh (slots 5..7 stay 0 forever)
  for (int i=tid; i<640; i+=512) ((float*)hb)[i] = 0.f;
  for (int i=tid; i<16*XSTR; i+=512) xh[i] = (_Float16)0;
  __syncthreads();

  float cc=0.f, hh=0.f;
  const int rdo  = n*40 + 8*quad;          // b128 read: dims 8q..8q+7 (f16 idx)
  const int wro  = n*40 + 8*quad + wv;     // b16 write: my dim
  const int xoff = n*XSTR;
  f16x8 xB;
  f32x4 Cx, Cy;

#define LSTM_STEP(CIN, COUT, RB, WB, TT2) do{ \
    const f16x8 bh_ = *(const f16x8*)(hb + (RB) + rdo); \
    COUT = __builtin_amdgcn_mfma_f32_16x16x32_f16(ax, xB, bi, 0,0,0); \
    xB = *(const f16x8*)(xh + xoff + ((TT2)&63)*8); \
    f32x4 C_ = __builtin_amdgcn_mfma_f32_16x16x32_f16(ah, bh_, CIN, 0,0,0); \
    /* ACT: C_[0]=i, C_[1]=f, C_[2]=g(2x), C_[3]=o; 5 exp2 + 3 rcp */ \
    const float ei=fexp2(C_[0]), ef=fexp2(C_[1]); \
    const float eg=fexp2(C_[2]), eo=fexp2(C_[3]); \
    const float Af=1.f+ef, Bi_=1.f+ei, G2=1.f+eg; \
    cc = cc*frcp(Af) + (2.f-G2)*frcp(Bi_*G2); \
    const float e2=fexp2((2.f*L2E)*cc); \
    const float E2=1.f+e2; \
    hh = (E2-2.f)*frcp((1.f+eo)*E2); \
    hb[(WB) + wro] = (_Float16)hh; \
    __syncthreads(); \
  }while(0)

  for (int tc = 0; tc < Tlen; tc += 64) {
    // stage 64 steps x 16 batches x 5 inputs -> f16 packed [n][t][8]
    // (prev chunk's final in-step barrier drained all xh reads)
    for (int i4 = tid; i4 < 1280; i4 += 512){
      const int nn = i4/80, e4 = i4%80;
      const float4 v4 = *(const float4*)(input + (size_t)(b0+nn)*(Tlen*NIN) + tc*NIN + e4*4);
      #pragma unroll
      for (int u=0;u<4;++u){
        const int e = e4*4+u;                        // 0..319 = t*5+c
        xh[nn*XSTR + (e/5)*8 + (e%5)] = (_Float16)((&v4.x)[u]);
      }
    }
    __syncthreads();
    // prime: Cx <- x-proj(t=0); xB <- x(1)
    {
      const f16x8 x0 = *(const f16x8*)(xh + xoff);
      Cx = __builtin_amdgcn_mfma_f32_16x16x32_f16(ax, x0, bi, 0,0,0);
      xB = *(const f16x8*)(xh + xoff + 8);
    }
    #pragma unroll 1
    for (int tl = 0; tl < 64; tl += 2) {
      LSTM_STEP(Cx, Cy, 0,   640, tl+2);   // even: read buf0, write buf1
      LSTM_STEP(Cy, Cx, 640, 0,   tl+3);   // odd : read buf1, write buf0
    }
  }
#undef LSTM_STEP

  // ---- tail: stash fp32 h,c (reuse xh as f32 scratch); project q,k,v ----
  float* hf = (float*)xh;      // [16][36]
  float* cf = hf + 16*36;
  {
    hf[n*36 + 8*quad + wv] = hh;   // dims 30,31 = exact 0 (harmless)
    cf[n*36 + 8*quad + wv] = cc;
  }
  __syncthreads();
  for (int i = tid; i < 16*NE; i += 512){
    const int nn = i/NE, d = i%NE;
    ho[(size_t)(b0+nn)*NE + d] = hf[nn*36 + d];
  }
  const float QS = 0.31622776601683794f;     // 1/sqrt(10)
  for (int i = tid; i < 90*16; i += 512){
    const int o  = i % 90;
    const int nn = i / 90;
    const float* wrow = in_proj_w + o*NE;
    const float* src  = (o < NE) ? &hf[nn*36] : &cf[nn*36];
    float acc = in_proj_b[o];
    #pragma unroll
    for (int k2=0;k2<NE;k2++) acc = fmaf(wrow[k2], src[k2], acc);
    const int b = b0 + nn;
    if (o < 30)      { qo[(o/10)*B10 + b*10 + (o%10)] = acc * QS; }
    else if (o < 60) { const int u=o-30; ko[(u/10)*B10 + b*10 + (u%10)] = acc; }
    else             { const int u=o-60; vo[(u/10)*B10 + b*10 + (u%10)] = acc; }
  }
}

// ---------------------------------------------------------------------------
// Kernel 2 (R10: cooperative LDS staging): flash attention partials.
// Thread = query. grid (16 qblocks, 3 heads, NS), block 256.
// ---------------------------------------------------------------------------
extern "C" __global__ void __launch_bounds__(256)
attn_part(const float* __restrict__ q, const float* __restrict__ k,
          const float* __restrict__ v, float* __restrict__ part, int nkeys)
{
  __shared__ __align__(16) float kst[640];   // 64 keys x 10
  __shared__ __align__(16) float vst[640];
  const int t    = threadIdx.x;
  const int qr   = blockIdx.x*256 + t;
  const int head = blockIdx.y;
  const int ks   = blockIdx.z;
  const float* kh = k + (size_t)head*B10;
  const float* vh = v + (size_t)head*B10;
  float qreg[10];
  {
    const float2* qp = (const float2*)(q + (size_t)head*B10 + (size_t)qr*10);
    #pragma unroll
    for (int i=0;i<5;i++){ float2 t2=qp[i]; qreg[2*i]=t2.x; qreg[2*i+1]=t2.y; }
  }
  float m = -INFINITY, l = 0.f, acc[10];
  #pragma unroll
  for (int d=0;d<10;d++) acc[d]=0.f;

  const int k0 = ks * nkeys;
  const int nt = nkeys >> 6;           // 64-key tiles
  #pragma unroll 1
  for (int ti=0; ti<nt; ++ti){
    const int kt0 = k0 + (ti<<6);
    __syncthreads();                   // previous tile's reads complete
    {
      const float4* ksrc = (const float4*)(kh + (size_t)kt0*10);
      const float4* vsrc = (const float4*)(vh + (size_t)kt0*10);
      for (int i=t; i<320; i+=256){
        if (i < 160) ((float4*)kst)[i]     = ksrc[i];
        else         ((float4*)vst)[i-160] = vsrc[i-160];
      }
    }
    __syncthreads();                   // staging visible
    #pragma unroll 1
    for (int c8=0; c8<64; c8+=8){
      float s[8];
      #pragma unroll
      for (int u=0;u<8;u++){
        const float2* kp = (const float2*)(kst + (c8+u)*10);
        float sv = 0.f;
        #pragma unroll
        for (int i=0;i<5;i++){ float2 kk=kp[i]; sv=fmaf(qreg[2*i],kk.x,sv); sv=fmaf(qreg[2*i+1],kk.y,sv); }
        s[u]=sv;
      }
      float mc = s[0];
      #pragma unroll
      for (int u=1;u<8;u++) mc = fmaxf(mc, s[u]);
      const float mnew = fmaxf(m, mc);
      const float corr = fexp2(L2E*(m - mnew));   // m=-inf first chunk -> 0
      l *= corr;
      #pragma unroll
      for (int d=0;d<10;d++) acc[d]*=corr;
      #pragma unroll
      for (int u=0;u<8;u++){
        const float p = fexp2(L2E*(s[u]-mnew));
        l += p;
        const float2* vp = (const float2*)(vst + (c8+u)*10);
        #pragma unroll
        for (int i=0;i<5;i++){ float2 vv=vp[i]; acc[2*i]=fmaf(p,vv.x,acc[2*i]); acc[2*i+1]=fmaf(p,vv.y,acc[2*i+1]); }
      }
      m = mnew;
    }
  }
  float* pp = part + ((size_t)(head*Bsz + qr)*gridDim.z + ks)*12;
  pp[0]=m; pp[1]=l;
  #pragma unroll
  for (int d=0;d<10;d++) pp[2+d]=acc[d];
}

// ---------------------------------------------------------------------------
// Kernel 3 (R10: LDS weights): fused merge + out_proj + LN + MLP + LN + head.
// One wave per row. Weight matrices staged to LDS once per block.
// ---------------------------------------------------------------------------
extern "C" __global__ void __launch_bounds__(256)
tail_k(const float* __restrict__ part, int ns, const float* __restrict__ hn,
       const float* __restrict__ out_proj_w, const float* __restrict__ out_proj_b,
       const float* __restrict__ fc1_w, const float* __restrict__ fc1_b,
       const float* __restrict__ fc2_w, const float* __restrict__ fc2_b,
       const float* __restrict__ ln_g, const float* __restrict__ ln_b,
       const float* __restrict__ out_w, const float* __restrict__ out_b,
       float* __restrict__ out)
{
  __shared__ __align__(16) float buf[4][32];
  __shared__ float wl[2880];   // [0]=out_proj_w 900, [900]=fc1_w, [1800]=fc2_w, [2700]=out_w 90
  const int tidb = threadIdx.x;
  for (int i=tidb;i<900;i+=256) wl[i]       = out_proj_w[i];
  for (int i=tidb;i<900;i+=256) wl[900+i]   = fc1_w[i];
  for (int i=tidb;i<900;i+=256) wl[1800+i]  = fc2_w[i];
  if (tidb < 90) wl[2700+tidb] = out_w[tidb];
  const int wave = tidb >> 6;
  const int lane = tidb & 63;
  const int b = blockIdx.x*4 + wave;
  const bool act = (lane < NE);
  if (lane < 32) buf[wave][lane] = 0.f;
  __syncthreads();
  if (act) {
    const int head = lane/10, dd = lane%10;
    const float* p = part + ((size_t)(head*Bsz + b)*ns)*12;
    float M = -INFINITY, L = 0.f, O = 0.f;
    for (int i=0;i<ns;i++){
      const float mi = p[i*12], li = p[i*12+1], ai = p[i*12+2+dd];
      const float Mn = fmaxf(M, mi);
      const float cw = fexp2(L2E*(M - Mn));
      const float wi = fexp2(L2E*(mi - Mn));
      L = fmaf(li, wi, L*cw);
      O = fmaf(ai, wi, O*cw);
      M = Mn;
    }
    buf[wave][lane] = O / L;
  }
  __builtin_amdgcn_wave_barrier();
  float arr[32];
  loadarr32(arr, &buf[wave][0]);
  const float hv = act ? hn[b*NE+lane] : 0.f;
  float x = 0.f;
  if (act) {
    float a = out_proj_b[lane];
    #pragma unroll
    for (int k2=0;k2<NE;k2++) a = fmaf(wl[lane*NE+k2], arr[k2], a);
    x = a + hv;                       // attn_out + h_n
  }
  // LN1
  __builtin_amdgcn_wave_barrier();
  if (act) buf[wave][lane] = x;
  __builtin_amdgcn_wave_barrier();
  loadarr32(arr, &buf[wave][0]);
  float s1=0.f, s2=0.f;
  #pragma unroll
  for (int k2=0;k2<32;k2++){ s1+=arr[k2]; s2=fmaf(arr[k2],arr[k2],s2); }
  float mu = s1*(1.f/30.f);
  float var = s2*(1.f/30.f) - mu*mu;
  float rs = rsqrtf(var + 1e-5f);
  float x1 = 0.f;
  if (act) x1 = fmaf((x-mu)*rs, ln_g[lane], ln_b[lane]);
  // fc1 + exact GELU
  __builtin_amdgcn_wave_barrier();
  if (act) buf[wave][lane] = x1;
  __builtin_amdgcn_wave_barrier();
  loadarr32(arr, &buf[wave][0]);
  float gv = 0.f;
  if (act) {
    float a = fc1_b[lane];
    #pragma unroll
    for (int k2=0;k2<NE;k2++) a = fmaf(wl[900+lane*NE+k2], arr[k2], a);
    gv = 0.5f*a*(1.f + erff(a*0.70710678118654752f));
  }
  // fc2
  __builtin_amdgcn_wave_barrier();
  if (act) buf[wave][lane] = gv;
  __builtin_amdgcn_wave_barrier();
  loadarr32(arr, &buf[wave][0]);
  float y = 0.f;
  if (act) {
    float a = fc2_b[lane];
    #pragma unroll
    for (int k2=0;k2<NE;k2++) a = fmaf(wl[1800+lane*NE+k2], arr[k2], a);
    y = x1 + a;                        // residual x1 + fc
  }
  // LN2
  __builtin_amdgcn_wave_barrier();
  if (act) buf[wave][lane] = y;
  __builtin_amdgcn_wave_barrier();
  loadarr32(arr, &buf[wave][0]);
  s1=0.f; s2=0.f;
  #pragma unroll
  for (int k2=0;k2<32;k2++){ s1+=arr[k2]; s2=fmaf(arr[k2],arr[k2],s2); }
  mu = s1*(1.f/30.f);
  var = s2*(1.f/30.f) - mu*mu;
  rs = rsqrtf(var + 1e-5f);
  float x2 = 0.f;
  if (act) x2 = fmaf((y-mu)*rs, ln_g[lane], ln_b[lane]);
  // head: [3,30]
  __builtin_amdgcn_wave_barrier();
  if (act) buf[wave][lane] = x2;
  __builtin_amdgcn_wave_barrier();
  loadarr32(arr, &buf[wave][0]);
  if (lane < 3) {
    float a = out_b[lane];
    #pragma unroll
    for (int k2=0;k2<NE;k2++) a = fmaf(wl[2700+lane*NE+k2], arr[k2], a);
    out[b*3 + lane] = a;
  }
}

extern "C" void kernel_launch(void* const* d_in, const int* in_sizes, int n_in,
                              void* d_out, int out_size, void* d_ws, size_t ws_size,
                              hipStream_t stream)
{
  const float* input      = (const float*)d_in[0];
  const float* w_ih       = (const float*)d_in[1];
  const float* w_hh       = (const float*)d_in[2];
  const float* b_ih       = (const float*)d_in[3];
  const float* b_hh       = (const float*)d_in[4];
  const float* in_proj_w  = (const float*)d_in[5];
  const float* in_proj_b  = (const float*)d_in[6];
  const float* out_proj_w = (const float*)d_in[7];
  const float* out_proj_b = (const float*)d_in[8];
  const float* fc1_w      = (const float*)d_in[9];
  const float* fc1_b      = (const float*)d_in[10];
  const float* fc2_w      = (const float*)d_in[11];
  const float* fc2_b      = (const float*)d_in[12];
  const float* ln_g       = (const float*)d_in[13];
  const float* ln_b       = (const float*)d_in[14];
  const float* out_w      = (const float*)d_in[15];
  const float* out_b      = (const float*)d_in[16];

  float* ws = (float*)d_ws;
  float* qo   = ws;                 // [3][4096][10]
  float* ko   = ws + 122880;        // [3][4096][10]
  float* vo   = ws + 245760;        // [3][4096][10]
  float* hn   = ws + 368640;        // [4096][30]
  float* part = ws + 491520;        // [3][4096][NS][12]

  const size_t need16 = ((size_t)491520 + (size_t)3*4096*16*12) * 4;
  const int NS = (ws_size >= need16) ? 16 : 8;

  lstm_k<<<Bsz/16, 512, 0, stream>>>(input, w_ih, w_hh, b_ih, b_hh,
                                     in_proj_w, in_proj_b, qo, ko, vo, hn);
  attn_part<<<dim3(Bsz/256, 3, NS), 256, 0, stream>>>(qo, ko, vo, part, Bsz/NS);
  tail_k<<<Bsz/4, 256, 0, stream>>>(part, NS, hn, out_proj_w, out_proj_b,
                                    fc1_w, fc1_b, fc2_w, fc2_b,
                                    ln_g, ln_b, out_w, out_b, (float*)d_out);
}

// Round 6
// 288.545 us; speedup vs baseline: 1.8037x; 1.0031x over previous
//
#include <hip/hip_runtime.h>
#include <math.h>

// Problem constants
#define Bsz  4096
#define Tlen 512
#define NE   30
#define NIN  5
#define HD10 10
#define B10  (Bsz*HD10)   // per-head plane: 40960 floats

typedef _Float16 h2v  __attribute__((ext_vector_type(2)));
typedef _Float16 f16x8 __attribute__((ext_vector_type(8)));
typedef float    f32x4 __attribute__((ext_vector_type(4)));

__device__ __forceinline__ float fexp2(float x){ return __builtin_amdgcn_exp2f(x); }
__device__ __forceinline__ float frcp (float x){ return __builtin_amdgcn_rcpf(x); }
#define L2E 1.4426950408889634f

__device__ __forceinline__ void loadarr32(float arr[32], const float* bufrow){
  const float4* p4 = (const float4*)bufrow;
  #pragma unroll
  for (int q4=0;q4<8;q4++){ float4 vv=p4[q4]; arr[4*q4]=vv.x; arr[4*q4+1]=vv.y; arr[4*q4+2]=vv.z; arr[4*q4+3]=vv.w; }
}

// ---------------------------------------------------------------------------
// Kernel 1 (R14, frozen): gate-packed MFMA rows -- 2 MFMA/wave/step.
// 146us measured. Per-step 685 cy = 256 trans-issue floor (16 insts/SIMD x
// ~16cy) + ~65 MFMA + ~340 lockstep latency (ds_read+ACT chain+barrier).
// ---------------------------------------------------------------------------
#define XSTR 520   // f16 stride per batch in xh (padded)

extern "C" __global__ void __launch_bounds__(512,1)
lstm_k(const float* __restrict__ input, const float* __restrict__ w_ih,
       const float* __restrict__ w_hh, const float* __restrict__ b_ih,
       const float* __restrict__ b_hh, const float* __restrict__ in_proj_w,
       const float* __restrict__ in_proj_b,
       float* __restrict__ qo, float* __restrict__ ko, float* __restrict__ vo,
       float* __restrict__ ho)
{
  __shared__ __align__(16) _Float16 hb[2*640];     // [parity][n*40 + dim]
  __shared__ __align__(16) _Float16 xh[16*XSTR];   // [n][t][8] f16 packed
  const int tid  = threadIdx.x;
  const int wv   = __builtin_amdgcn_readfirstlane(tid >> 6);   // 0..7 (SGPR)
  const int lane = tid & 63;
  const int n    = lane & 15;
  const int quad = lane >> 4;
  const int b0   = blockIdx.x * 16;

  // ---- gate-packed A-frags: A row m = (dim 8*(m>>2)+wv, gate m&3) ----
  f16x8 ah, ax;
  f32x4 bi;
  {
    const int r  = n & 3;               // gate for A row m=n
    const int qm = n >> 2;
    const int dA = 8*qm + wv;           // dim for A row m=n
    const float sG = (r==2) ? (-2.f*L2E) : (-L2E);   // g gate: x2 scale for tanh
    const bool rv = (dA < NE);
    const int grow = rv ? (r*NE + dA) : 0;
    #pragma unroll
    for (int j=0;j<8;++j){
      const int k = quad*8 + j;
      ah[j] = (rv && k < NE) ? (_Float16)(sG*w_hh[grow*NE + k]) : (_Float16)0;
      ax[j] = (rv && quad==0 && j < NIN) ? (_Float16)(sG*w_ih[grow*NIN + j]) : (_Float16)0;
    }
    const int d = 8*quad + wv;          // this lane's dim (D row 4q+rr = gate rr)
    #pragma unroll
    for (int rr=0;rr<4;++rr){
      const float sR = (rr==2) ? (-2.f*L2E) : (-L2E);
      bi[rr] = (d < NE) ? sR*(b_ih[rr*NE+d] + b_hh[rr*NE+d]) : 0.f;
    }
  }
  // zero h double-buffer and xh (slots 5..7 stay 0 forever)
  for (int i=tid; i<640; i+=512) ((float*)hb)[i] = 0.f;
  for (int i=tid; i<16*XSTR; i+=512) xh[i] = (_Float16)0;
  __syncthreads();

  float cc=0.f, hh=0.f;
  const int rdo  = n*40 + 8*quad;          // b128 read: dims 8q..8q+7 (f16 idx)
  const int wro  = n*40 + 8*quad + wv;     // b16 write: my dim
  const int xoff = n*XSTR;
  f16x8 xB;
  f32x4 Cx, Cy;

#define LSTM_STEP(CIN, COUT, RB, WB, TT2) do{ \
    const f16x8 bh_ = *(const f16x8*)(hb + (RB) + rdo); \
    COUT = __builtin_amdgcn_mfma_f32_16x16x32_f16(ax, xB, bi, 0,0,0); \
    xB = *(const f16x8*)(xh + xoff + ((TT2)&63)*8); \
    f32x4 C_ = __builtin_amdgcn_mfma_f32_16x16x32_f16(ah, bh_, CIN, 0,0,0); \
    /* ACT: C_[0]=i, C_[1]=f, C_[2]=g(2x), C_[3]=o; 5 exp2 + 3 rcp */ \
    const float ei=fexp2(C_[0]), ef=fexp2(C_[1]); \
    const float eg=fexp2(C_[2]), eo=fexp2(C_[3]); \
    const float Af=1.f+ef, Bi_=1.f+ei, G2=1.f+eg; \
    cc = cc*frcp(Af) + (2.f-G2)*frcp(Bi_*G2); \
    const float e2=fexp2((2.f*L2E)*cc); \
    const float E2=1.f+e2; \
    hh = (E2-2.f)*frcp((1.f+eo)*E2); \
    hb[(WB) + wro] = (_Float16)hh; \
    __syncthreads(); \
  }while(0)

  for (int tc = 0; tc < Tlen; tc += 64) {
    // stage 64 steps x 16 batches x 5 inputs -> f16 packed [n][t][8]
    // (prev chunk's final in-step barrier drained all xh reads)
    for (int i4 = tid; i4 < 1280; i4 += 512){
      const int nn = i4/80, e4 = i4%80;
      const float4 v4 = *(const float4*)(input + (size_t)(b0+nn)*(Tlen*NIN) + tc*NIN + e4*4);
      #pragma unroll
      for (int u=0;u<4;++u){
        const int e = e4*4+u;                        // 0..319 = t*5+c
        xh[nn*XSTR + (e/5)*8 + (e%5)] = (_Float16)((&v4.x)[u]);
      }
    }
    __syncthreads();
    // prime: Cx <- x-proj(t=0); xB <- x(1)
    {
      const f16x8 x0 = *(const f16x8*)(xh + xoff);
      Cx = __builtin_amdgcn_mfma_f32_16x16x32_f16(ax, x0, bi, 0,0,0);
      xB = *(const f16x8*)(xh + xoff + 8);
    }
    #pragma unroll 1
    for (int tl = 0; tl < 64; tl += 2) {
      LSTM_STEP(Cx, Cy, 0,   640, tl+2);   // even: read buf0, write buf1
      LSTM_STEP(Cy, Cx, 640, 0,   tl+3);   // odd : read buf1, write buf0
    }
  }
#undef LSTM_STEP

  // ---- tail: stash fp32 h,c (reuse xh as f32 scratch); project q,k,v ----
  float* hf = (float*)xh;      // [16][36]
  float* cf = hf + 16*36;
  {
    hf[n*36 + 8*quad + wv] = hh;   // dims 30,31 = exact 0 (harmless)
    cf[n*36 + 8*quad + wv] = cc;
  }
  __syncthreads();
  for (int i = tid; i < 16*NE; i += 512){
    const int nn = i/NE, d = i%NE;
    ho[(size_t)(b0+nn)*NE + d] = hf[nn*36 + d];
  }
  const float QS = 0.31622776601683794f;     // 1/sqrt(10)
  for (int i = tid; i < 90*16; i += 512){
    const int o  = i % 90;
    const int nn = i / 90;
    const float* wrow = in_proj_w + o*NE;
    const float* src  = (o < NE) ? &hf[nn*36] : &cf[nn*36];
    float acc = in_proj_b[o];
    #pragma unroll
    for (int k2=0;k2<NE;k2++) acc = fmaf(wrow[k2], src[k2], acc);
    const int b = b0 + nn;
    if (o < 30)      { qo[(o/10)*B10 + b*10 + (o%10)] = acc * QS; }
    else if (o < 60) { const int u=o-30; ko[(u/10)*B10 + b*10 + (u%10)] = acc; }
    else             { const int u=o-60; vo[(u/10)*B10 + b*10 + (u%10)] = acc; }
  }
}

// ---------------------------------------------------------------------------
// Kernel 2 (R15: latency-focused rework). The 143us non-lstm pool is mostly
// here; issue-floor model says ~25us/CU at 3 blocks/CU -> ~4x latency slack.
// Changes: NS 16->32 (6 blocks/CU, 2x wave-level hiding); K/V rows read in
// PAIRS via 5x float4 per 2 keys (10 -> 5 LDS insts/key); double-buffered
// tile staging (prefetch ti+1 during compute of ti, 1 barrier/tile);
// fused exp2 args; float4x3 part write.
// ---------------------------------------------------------------------------
extern "C" __global__ void __launch_bounds__(256)
attn_part(const float* __restrict__ q, const float* __restrict__ k,
          const float* __restrict__ v, float* __restrict__ part, int nkeys)
{
  __shared__ __align__(16) float kst[2][640];   // [buf][64 keys x 10]
  __shared__ __align__(16) float vst[2][640];
  const int t    = threadIdx.x;
  const int qr   = blockIdx.x*256 + t;
  const int head = blockIdx.y;
  const int ks   = blockIdx.z;
  const float* kh = k + (size_t)head*B10;
  const float* vh = v + (size_t)head*B10;
  float qreg[10];
  {
    const float2* qp = (const float2*)(q + (size_t)head*B10 + (size_t)qr*10);
    #pragma unroll
    for (int i=0;i<5;i++){ float2 t2=qp[i]; qreg[2*i]=t2.x; qreg[2*i+1]=t2.y; }
  }
  float m = -INFINITY, l = 0.f, acc[10];
  #pragma unroll
  for (int d=0;d<10;d++) acc[d]=0.f;

  const int k0 = ks * nkeys;
  const int nt = nkeys >> 6;           // 64-key tiles
  // prefetch tile 0 into buf 0
  {
    const float4* ksrc = (const float4*)(kh + (size_t)k0*10);
    const float4* vsrc = (const float4*)(vh + (size_t)k0*10);
    for (int i=t; i<320; i+=256){
      if (i < 160) ((float4*)kst[0])[i]     = ksrc[i];
      else         ((float4*)vst[0])[i-160] = vsrc[i-160];
    }
  }
  #pragma unroll 1
  for (int ti=0; ti<nt; ++ti){
    __syncthreads();                   // staged tile ti visible; buf^1 reads done
    const int cur = ti & 1;
    if (ti+1 < nt){                    // prefetch next tile into other buf
      const int kt = k0 + ((ti+1)<<6);
      const float4* ksrc = (const float4*)(kh + (size_t)kt*10);
      const float4* vsrc = (const float4*)(vh + (size_t)kt*10);
      for (int i=t; i<320; i+=256){
        if (i < 160) ((float4*)kst[cur^1])[i]     = ksrc[i];
        else         ((float4*)vst[cur^1])[i-160] = vsrc[i-160];
      }
    }
    const float* kb = kst[cur];
    const float* vb = vst[cur];
    #pragma unroll 1
    for (int c8=0; c8<64; c8+=8){
      float s[8];
      #pragma unroll
      for (int u2=0;u2<4;u2++){        // 2 keys per iter: 5x float4 = 20 floats
        const float4* kp = (const float4*)(kb + (c8+2*u2)*10);
        const float4 A=kp[0], B4=kp[1], C4=kp[2], D4=kp[3], E4=kp[4];
        float s0 = qreg[0]*A.x;
        s0=fmaf(qreg[1],A.y,s0);  s0=fmaf(qreg[2],A.z,s0);  s0=fmaf(qreg[3],A.w,s0);
        s0=fmaf(qreg[4],B4.x,s0); s0=fmaf(qreg[5],B4.y,s0); s0=fmaf(qreg[6],B4.z,s0);
        s0=fmaf(qreg[7],B4.w,s0); s0=fmaf(qreg[8],C4.x,s0); s0=fmaf(qreg[9],C4.y,s0);
        float s1 = qreg[0]*C4.z;
        s1=fmaf(qreg[1],C4.w,s1); s1=fmaf(qreg[2],D4.x,s1); s1=fmaf(qreg[3],D4.y,s1);
        s1=fmaf(qreg[4],D4.z,s1); s1=fmaf(qreg[5],D4.w,s1); s1=fmaf(qreg[6],E4.x,s1);
        s1=fmaf(qreg[7],E4.y,s1); s1=fmaf(qreg[8],E4.z,s1); s1=fmaf(qreg[9],E4.w,s1);
        s[2*u2]=s0; s[2*u2+1]=s1;
      }
      float mc = fmaxf(fmaxf(fmaxf(s[0],s[1]),fmaxf(s[2],s[3])),
                       fmaxf(fmaxf(s[4],s[5]),fmaxf(s[6],s[7])));
      const float mnew = fmaxf(m, mc);
      const float corr = fexp2(L2E*(m - mnew));   // m=-inf first chunk -> 0
      l *= corr;
      #pragma unroll
      for (int d=0;d<10;d++) acc[d]*=corr;
      const float mB = L2E*mnew;
      #pragma unroll
      for (int u2=0;u2<4;u2++){
        const float p0 = fexp2(fmaf(s[2*u2],  L2E, -mB));
        const float p1 = fexp2(fmaf(s[2*u2+1],L2E, -mB));
        l += p0; l += p1;
        const float4* vp = (const float4*)(vb + (c8+2*u2)*10);
        const float4 A=vp[0], B4=vp[1], C4=vp[2], D4=vp[3], E4=vp[4];
        acc[0]=fmaf(p0,A.x,acc[0]);  acc[1]=fmaf(p0,A.y,acc[1]);
        acc[2]=fmaf(p0,A.z,acc[2]);  acc[3]=fmaf(p0,A.w,acc[3]);
        acc[4]=fmaf(p0,B4.x,acc[4]); acc[5]=fmaf(p0,B4.y,acc[5]);
        acc[6]=fmaf(p0,B4.z,acc[6]); acc[7]=fmaf(p0,B4.w,acc[7]);
        acc[8]=fmaf(p0,C4.x,acc[8]); acc[9]=fmaf(p0,C4.y,acc[9]);
        acc[0]=fmaf(p1,C4.z,acc[0]); acc[1]=fmaf(p1,C4.w,acc[1]);
        acc[2]=fmaf(p1,D4.x,acc[2]); acc[3]=fmaf(p1,D4.y,acc[3]);
        acc[4]=fmaf(p1,D4.z,acc[4]); acc[5]=fmaf(p1,D4.w,acc[5]);
        acc[6]=fmaf(p1,E4.x,acc[6]); acc[7]=fmaf(p1,E4.y,acc[7]);
        acc[8]=fmaf(p1,E4.z,acc[8]); acc[9]=fmaf(p1,E4.w,acc[9]);
      }
      m = mnew;
    }
  }
  float4 w0,w1,w2;
  w0.x=m;      w0.y=l;      w0.z=acc[0]; w0.w=acc[1];
  w1.x=acc[2]; w1.y=acc[3]; w1.z=acc[4]; w1.w=acc[5];
  w2.x=acc[6]; w2.y=acc[7]; w2.z=acc[8]; w2.w=acc[9];
  float4* pp4 = (float4*)(part + ((size_t)(head*Bsz + qr)*gridDim.z + ks)*12);
  pp4[0]=w0; pp4[1]=w1; pp4[2]=w2;
}

// ---------------------------------------------------------------------------
// Kernel 3 (R10: LDS weights): fused merge + out_proj + LN + MLP + LN + head.
// One wave per row. Weight matrices staged to LDS once per block.
// ---------------------------------------------------------------------------
extern "C" __global__ void __launch_bounds__(256)
tail_k(const float* __restrict__ part, int ns, const float* __restrict__ hn,
       const float* __restrict__ out_proj_w, const float* __restrict__ out_proj_b,
       const float* __restrict__ fc1_w, const float* __restrict__ fc1_b,
       const float* __restrict__ fc2_w, const float* __restrict__ fc2_b,
       const float* __restrict__ ln_g, const float* __restrict__ ln_b,
       const float* __restrict__ out_w, const float* __restrict__ out_b,
       float* __restrict__ out)
{
  __shared__ __align__(16) float buf[4][32];
  __shared__ float wl[2880];   // [0]=out_proj_w 900, [900]=fc1_w, [1800]=fc2_w, [2700]=out_w 90
  const int tidb = threadIdx.x;
  for (int i=tidb;i<900;i+=256) wl[i]       = out_proj_w[i];
  for (int i=tidb;i<900;i+=256) wl[900+i]   = fc1_w[i];
  for (int i=tidb;i<900;i+=256) wl[1800+i]  = fc2_w[i];
  if (tidb < 90) wl[2700+tidb] = out_w[tidb];
  const int wave = tidb >> 6;
  const int lane = tidb & 63;
  const int b = blockIdx.x*4 + wave;
  const bool act = (lane < NE);
  if (lane < 32) buf[wave][lane] = 0.f;
  __syncthreads();
  if (act) {
    const int head = lane/10, dd = lane%10;
    const float* p = part + ((size_t)(head*Bsz + b)*ns)*12;
    float M = -INFINITY, L = 0.f, O = 0.f;
    for (int i=0;i<ns;i++){
      const float mi = p[i*12], li = p[i*12+1], ai = p[i*12+2+dd];
      const float Mn = fmaxf(M, mi);
      const float cw = fexp2(L2E*(M - Mn));
      const float wi = fexp2(L2E*(mi - Mn));
      L = fmaf(li, wi, L*cw);
      O = fmaf(ai, wi, O*cw);
      M = Mn;
    }
    buf[wave][lane] = O / L;
  }
  __builtin_amdgcn_wave_barrier();
  float arr[32];
  loadarr32(arr, &buf[wave][0]);
  const float hv = act ? hn[b*NE+lane] : 0.f;
  float x = 0.f;
  if (act) {
    float a = out_proj_b[lane];
    #pragma unroll
    for (int k2=0;k2<NE;k2++) a = fmaf(wl[lane*NE+k2], arr[k2], a);
    x = a + hv;                       // attn_out + h_n
  }
  // LN1
  __builtin_amdgcn_wave_barrier();
  if (act) buf[wave][lane] = x;
  __builtin_amdgcn_wave_barrier();
  loadarr32(arr, &buf[wave][0]);
  float s1=0.f, s2=0.f;
  #pragma unroll
  for (int k2=0;k2<32;k2++){ s1+=arr[k2]; s2=fmaf(arr[k2],arr[k2],s2); }
  float mu = s1*(1.f/30.f);
  float var = s2*(1.f/30.f) - mu*mu;
  float rs = rsqrtf(var + 1e-5f);
  float x1 = 0.f;
  if (act) x1 = fmaf((x-mu)*rs, ln_g[lane], ln_b[lane]);
  // fc1 + exact GELU
  __builtin_amdgcn_wave_barrier();
  if (act) buf[wave][lane] = x1;
  __builtin_amdgcn_wave_barrier();
  loadarr32(arr, &buf[wave][0]);
  float gv = 0.f;
  if (act) {
    float a = fc1_b[lane];
    #pragma unroll
    for (int k2=0;k2<NE;k2++) a = fmaf(wl[900+lane*NE+k2], arr[k2], a);
    gv = 0.5f*a*(1.f + erff(a*0.70710678118654752f));
  }
  // fc2
  __builtin_amdgcn_wave_barrier();
  if (act) buf[wave][lane] = gv;
  __builtin_amdgcn_wave_barrier();
  loadarr32(arr, &buf[wave][0]);
  float y = 0.f;
  if (act) {
    float a = fc2_b[lane];
    #pragma unroll
    for (int k2=0;k2<NE;k2++) a = fmaf(wl[1800+lane*NE+k2], arr[k2], a);
    y = x1 + a;                        // residual x1 + fc
  }
  // LN2
  __builtin_amdgcn_wave_barrier();
  if (act) buf[wave][lane] = y;
  __builtin_amdgcn_wave_barrier();
  loadarr32(arr, &buf[wave][0]);
  s1=0.f; s2=0.f;
  #pragma unroll
  for (int k2=0;k2<32;k2++){ s1+=arr[k2]; s2=fmaf(arr[k2],arr[k2],s2); }
  mu = s1*(1.f/30.f);
  var = s2*(1.f/30.f) - mu*mu;
  rs = rsqrtf(var + 1e-5f);
  float x2 = 0.f;
  if (act) x2 = fmaf((y-mu)*rs, ln_g[lane], ln_b[lane]);
  // head: [3,30]
  __builtin_amdgcn_wave_barrier();
  if (act) buf[wave][lane] = x2;
  __builtin_amdgcn_wave_barrier();
  loadarr32(arr, &buf[wave][0]);
  if (lane < 3) {
    float a = out_b[lane];
    #pragma unroll
    for (int k2=0;k2<NE;k2++) a = fmaf(wl[2700+lane*NE+k2], arr[k2], a);
    out[b*3 + lane] = a;
  }
}

extern "C" void kernel_launch(void* const* d_in, const int* in_sizes, int n_in,
                              void* d_out, int out_size, void* d_ws, size_t ws_size,
                              hipStream_t stream)
{
  const float* input      = (const float*)d_in[0];
  const float* w_ih       = (const float*)d_in[1];
  const float* w_hh       = (const float*)d_in[2];
  const float* b_ih       = (const float*)d_in[3];
  const float* b_hh       = (const float*)d_in[4];
  const float* in_proj_w  = (const float*)d_in[5];
  const float* in_proj_b  = (const float*)d_in[6];
  const float* out_proj_w = (const float*)d_in[7];
  const float* out_proj_b = (const float*)d_in[8];
  const float* fc1_w      = (const float*)d_in[9];
  const float* fc1_b      = (const float*)d_in[10];
  const float* fc2_w      = (const float*)d_in[11];
  const float* fc2_b      = (const float*)d_in[12];
  const float* ln_g       = (const float*)d_in[13];
  const float* ln_b       = (const float*)d_in[14];
  const float* out_w      = (const float*)d_in[15];
  const float* out_b      = (const float*)d_in[16];

  float* ws = (float*)d_ws;
  float* qo   = ws;                 // [3][4096][10]
  float* ko   = ws + 122880;        // [3][4096][10]
  float* vo   = ws + 245760;        // [3][4096][10]
  float* hn   = ws + 368640;        // [4096][30]
  float* part = ws + 491520;        // [3][4096][NS][12]

  const size_t need32 = ((size_t)491520 + (size_t)3*4096*32*12) * 4;
  const size_t need16 = ((size_t)491520 + (size_t)3*4096*16*12) * 4;
  const int NS = (ws_size >= need32) ? 32 : (ws_size >= need16) ? 16 : 8;

  lstm_k<<<Bsz/16, 512, 0, stream>>>(input, w_ih, w_hh, b_ih, b_hh,
                                     in_proj_w, in_proj_b, qo, ko, vo, hn);
  attn_part<<<dim3(Bsz/256, 3, NS), 256, 0, stream>>>(qo, ko, vo, part, Bsz/NS);
  tail_k<<<Bsz/4, 256, 0, stream>>>(part, NS, hn, out_proj_w, out_proj_b,
                                    fc1_w, fc1_b, fc2_w, fc2_b,
                                    ln_g, ln_b, out_w, out_b, (float*)d_out);
}

// Round 7
// 285.315 us; speedup vs baseline: 1.8241x; 1.0113x over previous
//
#include <hip/hip_runtime.h>
#include <math.h>

// Problem constants
#define Bsz  4096
#define Tlen 512
#define NE   30
#define NIN  5
#define HD10 10
#define B10  (Bsz*HD10)   // per-head plane: 40960 floats

typedef _Float16 h2v  __attribute__((ext_vector_type(2)));
typedef _Float16 f16x4 __attribute__((ext_vector_type(4)));
typedef _Float16 f16x8 __attribute__((ext_vector_type(8)));
typedef float    f32x4 __attribute__((ext_vector_type(4)));

__device__ __forceinline__ float fexp2(float x){ return __builtin_amdgcn_exp2f(x); }
__device__ __forceinline__ float frcp (float x){ return __builtin_amdgcn_rcpf(x); }
#define L2E 1.4426950408889634f

__device__ __forceinline__ void loadarr32(float arr[32], const float* bufrow){
  const float4* p4 = (const float4*)bufrow;
  #pragma unroll
  for (int q4=0;q4<8;q4++){ float4 vv=p4[q4]; arr[4*q4]=vv.x; arr[4*q4+1]=vv.y; arr[4*q4+2]=vv.z; arr[4*q4+3]=vv.w; }
}

// ---------------------------------------------------------------------------
// Kernel 1 (R16: merged-rcp ACT + stride-36 h rows + 2-ahead x prefetch).
// R15 finding: non-lstm residual is pinned ~135-143us across 5 attn/tail
// variants -> fixed harness overhead + small kernels. lstm_k is the only
// controllable cost. R14 step = 690 cy/SIMD: 256 trans issue (16x16cy) +
// ~100 other issue + ~330 exposed front (ds_read lat + MFMA lat + barrier).
// R16 cuts:
//  - ACT merged single-rcp: c' = (c*Bi*G2 + (1-eg)*Af)*rcp(Af*Bi*G2):
//    8 -> 7 trans/dim (exact algebra, products bounded ~1e9 << f32 max).
//  - hb row stride 40 -> 36 f16: stride-40 put all phase-0 words on 8 banks
//    (8-way conflict = 2.94x, the 1.155e7 SQ_LDS_BANK_CONFLICT). 18-word
//    rows spread over all 16 even banks -> 4-way (1.58x). bh read as two
//    8B-aligned f16x4 (b128 would need 16B align).
//  - xB/xB2 two-ahead shift register: xh read off the post-barrier window.
// Gate-packed MFMA rows (R14-verified): A row m=(dim 8*(m>>2)+wv, gate m&3);
// lane (q,n) D quad = 4 gate preacts for dim 8q+wv, batch n.
// Garbage dims 30,31 (qm=3, wv=6/7): zero A rows + zero bias -> preact 0 ->
// cc halves from 0 (stays 0), hh=(1-1)*r=0 exactly.
// Fragment layouts (m89/m120-verified):
//   A[m=lane&15][k=(lane>>4)*8+j], B[k=(lane>>4)*8+j][n=lane&15],
//   D[m=(lane>>4)*4+r][n=lane&15].
// ---------------------------------------------------------------------------
#define XSTR 520   // f16 stride per batch in xh (padded)
#define HSTR 36    // f16 stride per batch in hb (18 words: 4-way banks)

extern "C" __global__ void __launch_bounds__(512,1)
lstm_k(const float* __restrict__ input, const float* __restrict__ w_ih,
       const float* __restrict__ w_hh, const float* __restrict__ b_ih,
       const float* __restrict__ b_hh, const float* __restrict__ in_proj_w,
       const float* __restrict__ in_proj_b,
       float* __restrict__ qo, float* __restrict__ ko, float* __restrict__ vo,
       float* __restrict__ ho)
{
  __shared__ __align__(16) _Float16 hb[2*16*HSTR];   // [parity][n*HSTR + dim]
  __shared__ __align__(16) _Float16 xh[16*XSTR];     // [n][t][8] f16 packed
  const int tid  = threadIdx.x;
  const int wv   = __builtin_amdgcn_readfirstlane(tid >> 6);   // 0..7 (SGPR)
  const int lane = tid & 63;
  const int n    = lane & 15;
  const int quad = lane >> 4;
  const int b0   = blockIdx.x * 16;

  // ---- gate-packed A-frags: A row m = (dim 8*(m>>2)+wv, gate m&3) ----
  f16x8 ah, ax;
  f32x4 bi;
  {
    const int r  = n & 3;               // gate for A row m=n
    const int qm = n >> 2;
    const int dA = 8*qm + wv;           // dim for A row m=n
    const float sG = (r==2) ? (-2.f*L2E) : (-L2E);   // g gate: x2 scale for tanh
    const bool rv = (dA < NE);
    const int grow = rv ? (r*NE + dA) : 0;
    #pragma unroll
    for (int j=0;j<8;++j){
      const int k = quad*8 + j;
      ah[j] = (rv && k < NE) ? (_Float16)(sG*w_hh[grow*NE + k]) : (_Float16)0;
      ax[j] = (rv && quad==0 && j < NIN) ? (_Float16)(sG*w_ih[grow*NIN + j]) : (_Float16)0;
    }
    const int d = 8*quad + wv;          // this lane's dim (D row 4q+rr = gate rr)
    #pragma unroll
    for (int rr=0;rr<4;++rr){
      const float sR = (rr==2) ? (-2.f*L2E) : (-L2E);
      bi[rr] = (d < NE) ? sR*(b_ih[rr*NE+d] + b_hh[rr*NE+d]) : 0.f;
    }
  }
  // zero h double-buffer and xh (slots 5..7 stay 0 forever)
  for (int i=tid; i<2*16*HSTR; i+=512) hb[i] = (_Float16)0;
  for (int i=tid; i<16*XSTR; i+=512) xh[i] = (_Float16)0;
  __syncthreads();

  float cc=0.f, hh=0.f;
  const int rdo  = n*HSTR + 8*quad;        // two b64 reads: dims 8q..8q+7
  const int wro  = n*HSTR + 8*quad + wv;   // b16 write: my dim
  const int xoff = n*XSTR;
  f16x8 xB, xB2;
  f32x4 Cx, Cy;

#define LSTM_STEP(CIN, COUT, RB, WB, TT3) do{ \
    const f16x4 bl_ = *(const f16x4*)(hb + (RB) + rdo); \
    const f16x4 bu_ = *(const f16x4*)(hb + (RB) + rdo + 4); \
    union { f16x8 v; f16x4 h4[2]; } BU_; BU_.h4[0]=bl_; BU_.h4[1]=bu_; \
    COUT = __builtin_amdgcn_mfma_f32_16x16x32_f16(ax, xB, bi, 0,0,0); \
    xB = xB2; \
    xB2 = *(const f16x8*)(xh + xoff + ((TT3)&63)*8); \
    f32x4 C_ = __builtin_amdgcn_mfma_f32_16x16x32_f16(ah, BU_.v, CIN, 0,0,0); \
    /* ACT: C_[0]=i, C_[1]=f, C_[2]=g(2x), C_[3]=o; 5 exp2 + 2 rcp */ \
    const float ei=fexp2(C_[0]), ef=fexp2(C_[1]); \
    const float eg=fexp2(C_[2]), eo=fexp2(C_[3]); \
    const float Af=1.f+ef, Bi_=1.f+ei, G2=1.f+eg; \
    const float BG = Bi_*G2; \
    const float R_ = frcp(Af*BG); \
    const float t2_ = (1.f-eg)*Af; \
    cc = fmaf(cc, BG, t2_) * R_; \
    const float e2=fexp2((2.f*L2E)*cc); \
    const float E2=1.f+e2; \
    hh = (e2-1.f)*frcp((1.f+eo)*E2); \
    hb[(WB) + wro] = (_Float16)hh; \
    __syncthreads(); \
  }while(0)

  for (int tc = 0; tc < Tlen; tc += 64) {
    // stage 64 steps x 16 batches x 5 inputs -> f16 packed [n][t][8]
    // (prev chunk's final in-step barrier drained all xh reads)
    for (int i4 = tid; i4 < 1280; i4 += 512){
      const int nn = i4/80, e4 = i4%80;
      const float4 v4 = *(const float4*)(input + (size_t)(b0+nn)*(Tlen*NIN) + tc*NIN + e4*4);
      #pragma unroll
      for (int u=0;u<4;++u){
        const int e = e4*4+u;                        // 0..319 = t*5+c
        xh[nn*XSTR + (e/5)*8 + (e%5)] = (_Float16)((&v4.x)[u]);
      }
    }
    __syncthreads();
    // prime: Cx <- x-proj(t=0); xB <- x(1); xB2 <- x(2)
    {
      const f16x8 x0 = *(const f16x8*)(xh + xoff);
      Cx = __builtin_amdgcn_mfma_f32_16x16x32_f16(ax, x0, bi, 0,0,0);
      xB  = *(const f16x8*)(xh + xoff + 8);
      xB2 = *(const f16x8*)(xh + xoff + 16);
    }
    #pragma unroll 1
    for (int tl = 0; tl < 64; tl += 2) {
      LSTM_STEP(Cx, Cy, 0,        16*HSTR, tl+3);   // even: read buf0, write buf1
      LSTM_STEP(Cy, Cx, 16*HSTR,  0,       tl+4);   // odd : read buf1, write buf0
    }
  }
#undef LSTM_STEP

  // ---- tail: stash fp32 h,c (reuse xh as f32 scratch); project q,k,v ----
  float* hf = (float*)xh;      // [16][36]
  float* cf = hf + 16*36;
  {
    hf[n*36 + 8*quad + wv] = hh;   // dims 30,31 = exact 0 (harmless)
    cf[n*36 + 8*quad + wv] = cc;
  }
  __syncthreads();
  for (int i = tid; i < 16*NE; i += 512){
    const int nn = i/NE, d = i%NE;
    ho[(size_t)(b0+nn)*NE + d] = hf[nn*36 + d];
  }
  const float QS = 0.31622776601683794f;     // 1/sqrt(10)
  for (int i = tid; i < 90*16; i += 512){
    const int o  = i % 90;
    const int nn = i / 90;
    const float* wrow = in_proj_w + o*NE;
    const float* src  = (o < NE) ? &hf[nn*36] : &cf[nn*36];
    float acc = in_proj_b[o];
    #pragma unroll
    for (int k2=0;k2<NE;k2++) acc = fmaf(wrow[k2], src[k2], acc);
    const int b = b0 + nn;
    if (o < 30)      { qo[(o/10)*B10 + b*10 + (o%10)] = acc * QS; }
    else if (o < 60) { const int u=o-30; ko[(u/10)*B10 + b*10 + (u%10)] = acc; }
    else             { const int u=o-60; vo[(u/10)*B10 + b*10 + (u%10)] = acc; }
  }
}

// ---------------------------------------------------------------------------
// Kernel 2 (R15, frozen): flash attention partials. Near issue floor;
// R15's rework was neutral -> attn is not the controllable bottleneck.
// ---------------------------------------------------------------------------
extern "C" __global__ void __launch_bounds__(256)
attn_part(const float* __restrict__ q, const float* __restrict__ k,
          const float* __restrict__ v, float* __restrict__ part, int nkeys)
{
  __shared__ __align__(16) float kst[2][640];   // [buf][64 keys x 10]
  __shared__ __align__(16) float vst[2][640];
  const int t    = threadIdx.x;
  const int qr   = blockIdx.x*256 + t;
  const int head = blockIdx.y;
  const int ks   = blockIdx.z;
  const float* kh = k + (size_t)head*B10;
  const float* vh = v + (size_t)head*B10;
  float qreg[10];
  {
    const float2* qp = (const float2*)(q + (size_t)head*B10 + (size_t)qr*10);
    #pragma unroll
    for (int i=0;i<5;i++){ float2 t2=qp[i]; qreg[2*i]=t2.x; qreg[2*i+1]=t2.y; }
  }
  float m = -INFINITY, l = 0.f, acc[10];
  #pragma unroll
  for (int d=0;d<10;d++) acc[d]=0.f;

  const int k0 = ks * nkeys;
  const int nt = nkeys >> 6;           // 64-key tiles
  // prefetch tile 0 into buf 0
  {
    const float4* ksrc = (const float4*)(kh + (size_t)k0*10);
    const float4* vsrc = (const float4*)(vh + (size_t)k0*10);
    for (int i=t; i<320; i+=256){
      if (i < 160) ((float4*)kst[0])[i]     = ksrc[i];
      else         ((float4*)vst[0])[i-160] = vsrc[i-160];
    }
  }
  #pragma unroll 1
  for (int ti=0; ti<nt; ++ti){
    __syncthreads();                   // staged tile ti visible; buf^1 reads done
    const int cur = ti & 1;
    if (ti+1 < nt){                    // prefetch next tile into other buf
      const int kt = k0 + ((ti+1)<<6);
      const float4* ksrc = (const float4*)(kh + (size_t)kt*10);
      const float4* vsrc = (const float4*)(vh + (size_t)kt*10);
      for (int i=t; i<320; i+=256){
        if (i < 160) ((float4*)kst[cur^1])[i]     = ksrc[i];
        else         ((float4*)vst[cur^1])[i-160] = vsrc[i-160];
      }
    }
    const float* kb = kst[cur];
    const float* vb = vst[cur];
    #pragma unroll 1
    for (int c8=0; c8<64; c8+=8){
      float s[8];
      #pragma unroll
      for (int u2=0;u2<4;u2++){        // 2 keys per iter: 5x float4 = 20 floats
        const float4* kp = (const float4*)(kb + (c8+2*u2)*10);
        const float4 A=kp[0], B4=kp[1], C4=kp[2], D4=kp[3], E4=kp[4];
        float s0 = qreg[0]*A.x;
        s0=fmaf(qreg[1],A.y,s0);  s0=fmaf(qreg[2],A.z,s0);  s0=fmaf(qreg[3],A.w,s0);
        s0=fmaf(qreg[4],B4.x,s0); s0=fmaf(qreg[5],B4.y,s0); s0=fmaf(qreg[6],B4.z,s0);
        s0=fmaf(qreg[7],B4.w,s0); s0=fmaf(qreg[8],C4.x,s0); s0=fmaf(qreg[9],C4.y,s0);
        float s1 = qreg[0]*C4.z;
        s1=fmaf(qreg[1],C4.w,s1); s1=fmaf(qreg[2],D4.x,s1); s1=fmaf(qreg[3],D4.y,s1);
        s1=fmaf(qreg[4],D4.z,s1); s1=fmaf(qreg[5],D4.w,s1); s1=fmaf(qreg[6],E4.x,s1);
        s1=fmaf(qreg[7],E4.y,s1); s1=fmaf(qreg[8],E4.z,s1); s1=fmaf(qreg[9],E4.w,s1);
        s[2*u2]=s0; s[2*u2+1]=s1;
      }
      float mc = fmaxf(fmaxf(fmaxf(s[0],s[1]),fmaxf(s[2],s[3])),
                       fmaxf(fmaxf(s[4],s[5]),fmaxf(s[6],s[7])));
      const float mnew = fmaxf(m, mc);
      const float corr = fexp2(L2E*(m - mnew));   // m=-inf first chunk -> 0
      l *= corr;
      #pragma unroll
      for (int d=0;d<10;d++) acc[d]*=corr;
      const float mB = L2E*mnew;
      #pragma unroll
      for (int u2=0;u2<4;u2++){
        const float p0 = fexp2(fmaf(s[2*u2],  L2E, -mB));
        const float p1 = fexp2(fmaf(s[2*u2+1],L2E, -mB));
        l += p0; l += p1;
        const float4* vp = (const float4*)(vb + (c8+2*u2)*10);
        const float4 A=vp[0], B4=vp[1], C4=vp[2], D4=vp[3], E4=vp[4];
        acc[0]=fmaf(p0,A.x,acc[0]);  acc[1]=fmaf(p0,A.y,acc[1]);
        acc[2]=fmaf(p0,A.z,acc[2]);  acc[3]=fmaf(p0,A.w,acc[3]);
        acc[4]=fmaf(p0,B4.x,acc[4]); acc[5]=fmaf(p0,B4.y,acc[5]);
        acc[6]=fmaf(p0,B4.z,acc[6]); acc[7]=fmaf(p0,B4.w,acc[7]);
        acc[8]=fmaf(p0,C4.x,acc[8]); acc[9]=fmaf(p0,C4.y,acc[9]);
        acc[0]=fmaf(p1,C4.z,acc[0]); acc[1]=fmaf(p1,C4.w,acc[1]);
        acc[2]=fmaf(p1,D4.x,acc[2]); acc[3]=fmaf(p1,D4.y,acc[3]);
        acc[4]=fmaf(p1,D4.z,acc[4]); acc[5]=fmaf(p1,D4.w,acc[5]);
        acc[6]=fmaf(p1,E4.x,acc[6]); acc[7]=fmaf(p1,E4.y,acc[7]);
        acc[8]=fmaf(p1,E4.z,acc[8]); acc[9]=fmaf(p1,E4.w,acc[9]);
      }
      m = mnew;
    }
  }
  float4 w0,w1,w2;
  w0.x=m;      w0.y=l;      w0.z=acc[0]; w0.w=acc[1];
  w1.x=acc[2]; w1.y=acc[3]; w1.z=acc[4]; w1.w=acc[5];
  w2.x=acc[6]; w2.y=acc[7]; w2.z=acc[8]; w2.w=acc[9];
  float4* pp4 = (float4*)(part + ((size_t)(head*Bsz + qr)*gridDim.z + ks)*12);
  pp4[0]=w0; pp4[1]=w1; pp4[2]=w2;
}

// ---------------------------------------------------------------------------
// Kernel 3 (R10, frozen): fused merge + out_proj + LN + MLP + LN + head.
// ---------------------------------------------------------------------------
extern "C" __global__ void __launch_bounds__(256)
tail_k(const float* __restrict__ part, int ns, const float* __restrict__ hn,
       const float* __restrict__ out_proj_w, const float* __restrict__ out_proj_b,
       const float* __restrict__ fc1_w, const float* __restrict__ fc1_b,
       const float* __restrict__ fc2_w, const float* __restrict__ fc2_b,
       const float* __restrict__ ln_g, const float* __restrict__ ln_b,
       const float* __restrict__ out_w, const float* __restrict__ out_b,
       float* __restrict__ out)
{
  __shared__ __align__(16) float buf[4][32];
  __shared__ float wl[2880];   // [0]=out_proj_w 900, [900]=fc1_w, [1800]=fc2_w, [2700]=out_w 90
  const int tidb = threadIdx.x;
  for (int i=tidb;i<900;i+=256) wl[i]       = out_proj_w[i];
  for (int i=tidb;i<900;i+=256) wl[900+i]   = fc1_w[i];
  for (int i=tidb;i<900;i+=256) wl[1800+i]  = fc2_w[i];
  if (tidb < 90) wl[2700+tidb] = out_w[tidb];
  const int wave = tidb >> 6;
  const int lane = tidb & 63;
  const int b = blockIdx.x*4 + wave;
  const bool act = (lane < NE);
  if (lane < 32) buf[wave][lane] = 0.f;
  __syncthreads();
  if (act) {
    const int head = lane/10, dd = lane%10;
    const float* p = part + ((size_t)(head*Bsz + b)*ns)*12;
    float M = -INFINITY, L = 0.f, O = 0.f;
    for (int i=0;i<ns;i++){
      const float mi = p[i*12], li = p[i*12+1], ai = p[i*12+2+dd];
      const float Mn = fmaxf(M, mi);
      const float cw = fexp2(L2E*(M - Mn));
      const float wi = fexp2(L2E*(mi - Mn));
      L = fmaf(li, wi, L*cw);
      O = fmaf(ai, wi, O*cw);
      M = Mn;
    }
    buf[wave][lane] = O / L;
  }
  __builtin_amdgcn_wave_barrier();
  float arr[32];
  loadarr32(arr, &buf[wave][0]);
  const float hv = act ? hn[b*NE+lane] : 0.f;
  float x = 0.f;
  if (act) {
    float a = out_proj_b[lane];
    #pragma unroll
    for (int k2=0;k2<NE;k2++) a = fmaf(wl[lane*NE+k2], arr[k2], a);
    x = a + hv;                       // attn_out + h_n
  }
  // LN1
  __builtin_amdgcn_wave_barrier();
  if (act) buf[wave][lane] = x;
  __builtin_amdgcn_wave_barrier();
  loadarr32(arr, &buf[wave][0]);
  float s1=0.f, s2=0.f;
  #pragma unroll
  for (int k2=0;k2<32;k2++){ s1+=arr[k2]; s2=fmaf(arr[k2],arr[k2],s2); }
  float mu = s1*(1.f/30.f);
  float var = s2*(1.f/30.f) - mu*mu;
  float rs = rsqrtf(var + 1e-5f);
  float x1 = 0.f;
  if (act) x1 = fmaf((x-mu)*rs, ln_g[lane], ln_b[lane]);
  // fc1 + exact GELU
  __builtin_amdgcn_wave_barrier();
  if (act) buf[wave][lane] = x1;
  __builtin_amdgcn_wave_barrier();
  loadarr32(arr, &buf[wave][0]);
  float gv = 0.f;
  if (act) {
    float a = fc1_b[lane];
    #pragma unroll
    for (int k2=0;k2<NE;k2++) a = fmaf(wl[900+lane*NE+k2], arr[k2], a);
    gv = 0.5f*a*(1.f + erff(a*0.70710678118654752f));
  }
  // fc2
  __builtin_amdgcn_wave_barrier();
  if (act) buf[wave][lane] = gv;
  __builtin_amdgcn_wave_barrier();
  loadarr32(arr, &buf[wave][0]);
  float y = 0.f;
  if (act) {
    float a = fc2_b[lane];
    #pragma unroll
    for (int k2=0;k2<NE;k2++) a = fmaf(wl[1800+lane*NE+k2], arr[k2], a);
    y = x1 + a;                        // residual x1 + fc
  }
  // LN2
  __builtin_amdgcn_wave_barrier();
  if (act) buf[wave][lane] = y;
  __builtin_amdgcn_wave_barrier();
  loadarr32(arr, &buf[wave][0]);
  s1=0.f; s2=0.f;
  #pragma unroll
  for (int k2=0;k2<32;k2++){ s1+=arr[k2]; s2=fmaf(arr[k2],arr[k2],s2); }
  mu = s1*(1.f/30.f);
  var = s2*(1.f/30.f) - mu*mu;
  rs = rsqrtf(var + 1e-5f);
  float x2 = 0.f;
  if (act) x2 = fmaf((y-mu)*rs, ln_g[lane], ln_b[lane]);
  // head: [3,30]
  __builtin_amdgcn_wave_barrier();
  if (act) buf[wave][lane] = x2;
  __builtin_amdgcn_wave_barrier();
  loadarr32(arr, &buf[wave][0]);
  if (lane < 3) {
    float a = out_b[lane];
    #pragma unroll
    for (int k2=0;k2<NE;k2++) a = fmaf(wl[2700+lane*NE+k2], arr[k2], a);
    out[b*3 + lane] = a;
  }
}

extern "C" void kernel_launch(void* const* d_in, const int* in_sizes, int n_in,
                              void* d_out, int out_size, void* d_ws, size_t ws_size,
                              hipStream_t stream)
{
  const float* input      = (const float*)d_in[0];
  const float* w_ih       = (const float*)d_in[1];
  const float* w_hh       = (const float*)d_in[2];
  const float* b_ih       = (const float*)d_in[3];
  const float* b_hh       = (const float*)d_in[4];
  const float* in_proj_w  = (const float*)d_in[5];
  const float* in_proj_b  = (const float*)d_in[6];
  const float* out_proj_w = (const float*)d_in[7];
  const float* out_proj_b = (const float*)d_in[8];
  const float* fc1_w      = (const float*)d_in[9];
  const float* fc1_b      = (const float*)d_in[10];
  const float* fc2_w      = (const float*)d_in[11];
  const float* fc2_b      = (const float*)d_in[12];
  const float* ln_g       = (const float*)d_in[13];
  const float* ln_b       = (const float*)d_in[14];
  const float* out_w      = (const float*)d_in[15];
  const float* out_b      = (const float*)d_in[16];

  float* ws = (float*)d_ws;
  float* qo   = ws;                 // [3][4096][10]
  float* ko   = ws + 122880;        // [3][4096][10]
  float* vo   = ws + 245760;        // [3][4096][10]
  float* hn   = ws + 368640;        // [4096][30]
  float* part = ws + 491520;        // [3][4096][NS][12]

  const size_t need32 = ((size_t)491520 + (size_t)3*4096*32*12) * 4;
  const size_t need16 = ((size_t)491520 + (size_t)3*4096*16*12) * 4;
  const int NS = (ws_size >= need32) ? 32 : (ws_size >= need16) ? 16 : 8;

  lstm_k<<<Bsz/16, 512, 0, stream>>>(input, w_ih, w_hh, b_ih, b_hh,
                                     in_proj_w, in_proj_b, qo, ko, vo, hn);
  attn_part<<<dim3(Bsz/256, 3, NS), 256, 0, stream>>>(qo, ko, vo, part, Bsz/NS);
  tail_k<<<Bsz/4, 256, 0, stream>>>(part, NS, hn, out_proj_w, out_proj_b,
                                    fc1_w, fc1_b, fc2_w, fc2_b,
                                    ln_g, ln_b, out_w, out_b, (float*)d_out);
}